// Round 7
// baseline (6004.232 us; speedup 1.0000x reference)
//
#include <hip/hip_runtime.h>

using bf16x8 = __attribute__((ext_vector_type(8))) __bf16;
using u16x8  = __attribute__((ext_vector_type(8))) unsigned short;
using f32x4  = __attribute__((ext_vector_type(4))) float;
using f32x2  = __attribute__((ext_vector_type(2))) float;

#define DEV static __device__ __forceinline__

constexpr int NN = 98304;     // total nodes  (512 pairs * 192)
constexpr int NE = 786432;    // total edges  (8 * NN)
constexpr int NB = 512;       // pairs

// ---------------- workspace layout (bytes) ----------------
constexpr size_t OFF_HB  = 0;                                  // hb : NN*128 bf16 (25.2MB)
constexpr size_t OFF_AGG = OFF_HB + (size_t)NN*128*2;          // agg: NN*128 f32  (50.3MB)
constexpr size_t OFF_TH  = OFF_AGG;                            // Th aliases agg[0:25.2MB]
constexpr size_t OFF_TL  = OFF_AGG + (size_t)NN*128*2;         // Tl aliases agg[25.2:50.3MB]
constexpr size_t OFF_W   = OFF_AGG + (size_t)NN*128*4;         // weight area

constexpr size_t WO_W1TM = 0;                                  // [256][320] bf16
constexpr size_t WO_W1TR = WO_W1TM + (size_t)81920*2;
constexpr size_t WO_W2TM = WO_W1TR + (size_t)81920*2;          // [128][256] bf16
constexpr size_t WO_W2TR = WO_W2TM + (size_t)32768*2;
constexpr size_t WO_W1TU = WO_W2TR + (size_t)32768*2;          // [256][256] bf16
constexpr size_t WO_W2TU = WO_W1TU + (size_t)65536*2;          // [128][256] bf16
constexpr size_t WO_WNT  = WO_W2TU + (size_t)32768*2;          // [128][32] bf16
constexpr size_t WO_WETP = WO_WNT  + (size_t)4096*2;           // [64][32] bf16 (k>=16 zero)
constexpr size_t WO_FC1F = WO_WETP + (size_t)2048*2;           // [128][128] f32
constexpr size_t WO_FC2F = WO_FC1F + (size_t)16384*4;
constexpr size_t WO_BNF  = WO_FC2F + (size_t)16384*4;          // biases f32
constexpr size_t WO_BEF  = WO_BNF + 128*4;
constexpr size_t WO_B1M  = WO_BEF + 64*4;
constexpr size_t WO_B2M  = WO_B1M + 256*4;
constexpr size_t WO_B1R  = WO_B2M + 128*4;
constexpr size_t WO_B2R  = WO_B1R + 256*4;
constexpr size_t WO_B1U  = WO_B2R + 128*4;
constexpr size_t WO_B2U  = WO_B1U + 256*4;
constexpr size_t WO_FC1B = WO_B2U + 128*4;
constexpr size_t WO_FC2B = WO_FC1B + 128*4;
constexpr size_t WO_FLAG = WO_FC2B + 128*4;                    // int dtype flag
constexpr size_t WO_END  = WO_FLAG + 16;

constexpr size_t OFF_HL  = OFF_W + WO_END;                     // hl : NN*128 bf16 (full only)
constexpr size_t WS_MINI = OFF_HL;                             // ~76.3 MB
constexpr size_t WS_FULL = OFF_HL + (size_t)NN*128*2;          // ~101.5 MB

// ---------------- CSR region (appended; only if ws allows) ----------------
constexpr int    SCAN_CHUNKS= NN/256;                          // 384
constexpr size_t CSR_INTS   = (size_t)2*(NN+1) + (size_t)2*NN + (size_t)2*NE + 768;
constexpr size_t CSR_BYTES  = CSR_INTS*4;                      // ~7.5 MB
constexpr size_t WS_FULL_G  = WS_FULL + CSR_BYTES;             // ~109.3 MB (confirmed avail)
constexpr size_t WS_MINI_G  = WS_MINI + CSR_BYTES;             // ~84.2 MB

DEV unsigned short f2bf(float f){
  unsigned u = __float_as_uint(f);
  u += 0x7fffu + ((u >> 16) & 1u);          // RNE
  return (unsigned short)(u >> 16);
}
DEV float bf2f(unsigned short s){ return __uint_as_float(((unsigned)s) << 16); }

DEV unsigned short ldbf(const void* p, size_t i, int fl){
  return fl ? ((const unsigned short*)p)[i] : f2bf(((const float*)p)[i]);
}
DEV float ldf(const void* p, size_t i, int fl){
  return fl ? bf2f(((const unsigned short*)p)[i]) : ((const float*)p)[i];
}

DEV f32x4 mfma16(u16x8 a, u16x8 b, f32x4 c){
  bf16x8 A, B;
  __builtin_memcpy(&A, &a, 16);
  __builtin_memcpy(&B, &b, 16);
  return __builtin_amdgcn_mfma_f32_16x16x32_bf16(A, B, c, 0, 0, 0);
}

// ============================================================ dtype probe
__global__ void k_dtype(const unsigned short* nf_u16, int* flag){
  if (threadIdx.x != 0 || blockIdx.x != 0) return;
  int sane = 0;
  for (int i = 0; i < 64; ++i){
    unsigned short v = nf_u16[2*i];
    int e = (v >> 7) & 0xFF;
    if (e >= 0x70 && e <= 0x8E) sane++;
  }
  *flag = (sane >= 32) ? 1 : 0;
}

// ============================================================ ws-too-small sentinel
__global__ void k_sent(float* out){
  int i = blockIdx.x*256 + threadIdx.x;
  if (i < NB) out[i] = 10000.f;
}

// ============================================================ canary
__global__ void k_canary(void* out, const int* flag){
  int i = blockIdx.x*256 + threadIdx.x;
  if (i < NB){
    if (*flag) ((unsigned short*)out)[i] = (unsigned short)0x4580u;
    else       ((float*)out)[i] = 4096.f;
  }
}

// ============================================================ zero agg
__global__ void k_zero(float* agg){
  f32x4* p = (f32x4*)agg;
  int gtid = blockIdx.x*256 + threadIdx.x;
  for (int i = gtid; i < NN*128/4; i += 786432){
    f32x4 z = {0.f, 0.f, 0.f, 0.f};
    p[i] = z;
  }
}

// ============================================================ prep: transpose/convert weights
__global__ void k_prep(
  const void* enc_node_w, const void* enc_node_b,
  const void* enc_edge_w, const void* enc_edge_b,
  const void* msg_w1, const void* msg_b1,
  const void* msg_w2, const void* msg_b2,
  const void* rmsg_w1, const void* rmsg_b1,
  const void* rmsg_w2, const void* rmsg_b2,
  const void* upd_w1, const void* upd_b1,
  const void* upd_w2, const void* upd_b2,
  const void* fc1_w, const void* fc1_b,
  const void* fc2_w, const void* fc2_b,
  char* wsb)
{
  int fl = *(const int*)(wsb + OFF_W + WO_FLAG);
  int i = blockIdx.x*256 + threadIdx.x;
  unsigned short* W1Tm = (unsigned short*)(wsb + OFF_W + WO_W1TM);
  unsigned short* W1Tr = (unsigned short*)(wsb + OFF_W + WO_W1TR);
  unsigned short* W2Tm = (unsigned short*)(wsb + OFF_W + WO_W2TM);
  unsigned short* W2Tr = (unsigned short*)(wsb + OFF_W + WO_W2TR);
  unsigned short* W1Tu = (unsigned short*)(wsb + OFF_W + WO_W1TU);
  unsigned short* W2Tu = (unsigned short*)(wsb + OFF_W + WO_W2TU);
  unsigned short* WnT  = (unsigned short*)(wsb + OFF_W + WO_WNT);
  unsigned short* WeTp = (unsigned short*)(wsb + OFF_W + WO_WETP);
  float* fc1f = (float*)(wsb + OFF_W + WO_FC1F);
  float* fc2f = (float*)(wsb + OFF_W + WO_FC2F);
  float* bnf  = (float*)(wsb + OFF_W + WO_BNF);
  float* bef  = (float*)(wsb + OFF_W + WO_BEF);
  float* b1m  = (float*)(wsb + OFF_W + WO_B1M);
  float* b2m  = (float*)(wsb + OFF_W + WO_B2M);
  float* b1r  = (float*)(wsb + OFF_W + WO_B1R);
  float* b2r  = (float*)(wsb + OFF_W + WO_B2R);
  float* b1u  = (float*)(wsb + OFF_W + WO_B1U);
  float* b2u  = (float*)(wsb + OFF_W + WO_B2U);
  float* f1b  = (float*)(wsb + OFF_W + WO_FC1B);
  float* f2b  = (float*)(wsb + OFF_W + WO_FC2B);

  if (i < 81920){ W1Tm[i] = ldbf(msg_w1,  (size_t)(i%320)*256 + (i/320), fl); return; } i -= 81920;
  if (i < 81920){ W1Tr[i] = ldbf(rmsg_w1, (size_t)(i%320)*256 + (i/320), fl); return; } i -= 81920;
  if (i < 32768){ W2Tm[i] = ldbf(msg_w2,  (size_t)(i%256)*128 + (i/256), fl); return; } i -= 32768;
  if (i < 32768){ W2Tr[i] = ldbf(rmsg_w2, (size_t)(i%256)*128 + (i/256), fl); return; } i -= 32768;
  if (i < 65536){ W1Tu[i] = ldbf(upd_w1,  (size_t)(i%256)*256 + (i/256), fl); return; } i -= 65536;
  if (i < 32768){ W2Tu[i] = ldbf(upd_w2,  (size_t)(i%256)*128 + (i/256), fl); return; } i -= 32768;
  if (i <  4096){ WnT[i]  = ldbf(enc_node_w, (size_t)(i%32)*128 + (i/32), fl); return; } i -= 4096;
  if (i <  2048){ int k = i%32, n = i/32;
                  WeTp[i] = (k<16) ? ldbf(enc_edge_w, (size_t)k*64 + n, fl) : (unsigned short)0; return; } i -= 2048;
  if (i < 16384){ fc1f[i] = ldf(fc1_w, i, fl); return; } i -= 16384;
  if (i < 16384){ fc2f[i] = ldf(fc2_w, i, fl); return; } i -= 16384;
  if (i <   128){ bnf[i] = ldf(enc_node_b, i, fl); return; } i -= 128;
  if (i <    64){ bef[i] = ldf(enc_edge_b, i, fl); return; } i -= 64;
  if (i <   256){ b1m[i] = ldf(msg_b1, i, fl); return; } i -= 256;
  if (i <   128){ b2m[i] = ldf(msg_b2, i, fl); return; } i -= 128;
  if (i <   256){ b1r[i] = ldf(rmsg_b1, i, fl); return; } i -= 256;
  if (i <   128){ b2r[i] = ldf(rmsg_b2, i, fl); return; } i -= 128;
  if (i <   256){ b1u[i] = ldf(upd_b1, i, fl); return; } i -= 256;
  if (i <   128){ b2u[i] = ldf(upd_b2, i, fl); return; } i -= 128;
  if (i <   128){ f1b[i] = ldf(fc1_b, i, fl); return; } i -= 128;
  if (i <   128){ f2b[i] = ldf(fc2_b, i, fl); return; }
}

// ============================================================ CSR build (one-time per call)
__global__ void k_csr_zero(int* cur0, int* cur1){
  int i = blockIdx.x*256 + threadIdx.x;
  if (i < NN){ cur0[i] = 0; cur1[i] = 0; }
}
__global__ void k_csr_count(const int* from_idx, const int* to_idx, int* cur0, int* cur1){
  int e = blockIdx.x*256 + threadIdx.x;
  if (e < NE){
    atomicAdd(&cur0[to_idx[e]], 1);
    atomicAdd(&cur1[from_idx[e]], 1);
  }
}
__global__ void k_scan1(const int* cur0, const int* cur1, int* csum){
  __shared__ int red[256];
  int b = blockIdx.x, tid = threadIdx.x;
  const int* c = (b >= SCAN_CHUNKS) ? cur1 : cur0;
  int cb = (b >= SCAN_CHUNKS) ? (b - SCAN_CHUNKS) : b;
  red[tid] = c[cb*256 + tid];
  __syncthreads();
  for (int off = 128; off > 0; off >>= 1){
    if (tid < off) red[tid] += red[tid + off];
    __syncthreads();
  }
  if (tid == 0) csum[b] = red[0];
}
__global__ void k_scan2(int* csum, int* offs0, int* offs1){
  int wv = threadIdx.x >> 6, lane = threadIdx.x & 63;
  if (wv >= 2) return;
  int basei = wv * SCAN_CHUNKS;
  int carry = 0;
  for (int j = 0; j < SCAN_CHUNKS/64; ++j){
    int x = csum[basei + j*64 + lane];
    int s = x;
    for (int off = 1; off < 64; off <<= 1){
      int t = __shfl_up(s, off, 64);
      if (lane >= off) s += t;
    }
    csum[basei + j*64 + lane] = s - x + carry;   // exclusive
    carry += __shfl(s, 63, 64);
  }
  if (lane == 0){
    if (wv == 0) offs0[NN] = carry; else offs1[NN] = carry;
  }
}
__global__ void k_scan3(int* cur0, int* cur1, const int* csum, int* offs0, int* offs1){
  __shared__ int s[256];
  int b = blockIdx.x, tid = threadIdx.x;
  int dir = (b >= SCAN_CHUNKS) ? 1 : 0;
  int cb  = dir ? (b - SCAN_CHUNKS) : b;
  int* c    = dir ? cur1 : cur0;
  int* offs = dir ? offs1 : offs0;
  int v = c[cb*256 + tid];
  s[tid] = v;
  __syncthreads();
  for (int off = 1; off < 256; off <<= 1){
    int t = (tid >= off) ? s[tid - off] : 0;
    __syncthreads();
    s[tid] += t;
    __syncthreads();
  }
  int excl = s[tid] - v + csum[b];
  offs[cb*256 + tid] = excl;
  c[cb*256 + tid] = excl;          // cursor = start offset
}
__global__ void k_csr_fill(const int* from_idx, const int* to_idx,
                           int* cur0, int* cur1, int* ent0, int* ent1){
  int e = blockIdx.x*256 + threadIdx.x;
  if (e < NE){
    int p0 = atomicAdd(&cur0[to_idx[e]], 1);   ent0[p0] = e;
    int p1 = atomicAdd(&cur1[from_idx[e]], 1); ent1[p1] = e;
  }
}

// ============================================================ node encoder
__global__ void __launch_bounds__(256) k_enc_node(
  const void* nf, const unsigned short* wnt, const float* bnf,
  unsigned short* hb, unsigned short* hl, int has_hl, const int* flag)
{
  int fl = *flag;
  const u16x8* wnt8 = (const u16x8*)wnt;
  int tid = threadIdx.x, wv = tid>>6, lane = tid&63, quad = lane>>4, l15 = lane&15;
  int n0 = blockIdx.x*64;
  f32x4 acc[4][2];
  for (int a=0;a<4;a++){ f32x4 z = {0.f,0.f,0.f,0.f}; acc[a][0]=z; acc[a][1]=z; }
  u16x8 av[4], bv[2];
  if (fl){
    const u16x8* nf8 = (const u16x8*)nf;
    for (int mt=0; mt<4; ++mt) av[mt] = nf8[(size_t)(n0 + mt*16 + l15)*4 + quad];
  } else {
    const float* nff = (const float*)nf;
    for (int mt=0; mt<4; ++mt){
      const float* rp = nff + (size_t)(n0 + mt*16 + l15)*32 + quad*8;
      u16x8 v;
      for (int j=0;j<8;j++) v[j] = f2bf(rp[j]);
      av[mt] = v;
    }
  }
  for (int nt=0; nt<2; ++nt) bv[nt] = wnt8[(size_t)(wv*32 + nt*16 + l15)*4 + quad];
  for (int mt=0; mt<4; ++mt)
    for (int nt=0; nt<2; ++nt)
      acc[mt][nt] = mfma16(av[mt], bv[nt], acc[mt][nt]);
  for (int mt=0; mt<4; ++mt)
    for (int nt=0; nt<2; ++nt){
      int n = wv*32 + nt*16 + l15;
      float bias = bnf[n];
      for (int r=0;r<4;r++){
        int m = mt*16 + quad*4 + r;
        float v = acc[mt][nt][r] + bias;
        size_t idx = (size_t)(n0+m)*128 + n;
        unsigned short hi = f2bf(v);
        hb[idx] = hi;
        if (has_hl) hl[idx] = f2bf(v - bf2f(hi));
      }
    }
}

// ============================================================ message kernel (ATOMIC FALLBACK)
__global__ void __launch_bounds__(256) k_msg(
  const unsigned short* hbg, const void* efg,
  const int* from_idx, const int* to_idx,
  const unsigned short* w1tm, const unsigned short* w1tr,
  const unsigned short* w2tm, const unsigned short* w2tr,
  const unsigned short* wetp, const float* bef,
  const float* b1m, const float* b2m, const float* b1r, const float* b2r,
  float* agg, const int* flag)
{
  __shared__ __align__(16) unsigned short XsB[40*32*8];   // 20480 B
  __shared__ __align__(16) unsigned short HsB[32*32*8];   // 16384 B
  __shared__ int fromS[32], toS[32];
  int fl = *flag;
  u16x8* Xs = (u16x8*)XsB;
  u16x8* Hs = (u16x8*)HsB;
  const u16x8* hb8   = (const u16x8*)hbg;
  const u16x8* wetp8 = (const u16x8*)wetp;
  const u16x8* w1tm8 = (const u16x8*)w1tm;
  const u16x8* w1tr8 = (const u16x8*)w1tr;
  const u16x8* w2tm8 = (const u16x8*)w2tm;
  const u16x8* w2tr8 = (const u16x8*)w2tr;

  int tid = threadIdx.x;
  int e0 = blockIdx.x*32;
  if (tid < 32) fromS[tid] = from_idx[e0 + tid];
  else if (tid < 64) toS[tid-32] = to_idx[e0 + tid - 32];
  __syncthreads();
  int m = tid & 31, g = tid >> 5;
  int wv = tid>>6, lane = tid&63, quad = lane>>4, l15 = lane&15;
  u16x8 zero8 = {0,0,0,0,0,0,0,0};

  for (int j=0; j<4; ++j){
    int kb = g + 8*j;
    u16x8 v = (kb < 16) ? hb8[(size_t)fromS[m]*16 + kb]
                        : hb8[(size_t)toS[m]*16 + (kb-16)];
    Xs[kb*32 + m] = v;
  }
  {
    f32x4 accE[2];
    for (int a=0;a<2;a++){ f32x4 z = {0.f,0.f,0.f,0.f}; accE[a]=z; }
    u16x8 bvE = wetp8[(size_t)(wv*16 + l15)*4 + quad];
    for (int mt=0; mt<2; ++mt){
      u16x8 avE = zero8;
      if (quad < 2){
        if (fl){
          avE = ((const u16x8*)efg)[(size_t)(e0 + mt*16 + l15)*2 + quad];
        } else {
          const float* ep = (const float*)efg + (size_t)(e0 + mt*16 + l15)*16 + quad*8;
          u16x8 v;
          for (int j=0;j<8;j++) v[j] = f2bf(ep[j]);
          avE = v;
        }
      }
      accE[mt] = mfma16(avE, bvE, accE[mt]);
    }
    int n = wv*16 + l15;
    float bias = bef[n];
    for (int mt=0; mt<2; ++mt)
      for (int r=0;r<4;r++){
        int me = mt*16 + quad*4 + r;
        XsB[((32 + (n>>3))*32 + me)*8 + (n&7)] = f2bf(accE[mt][r] + bias);
      }
  }
  __syncthreads();

  for (int dir=0; dir<2; ++dir){
    const u16x8* W1T = dir ? w1tr8 : w1tm8;
    const u16x8* W2T = dir ? w2tr8 : w2tm8;
    const float* B1  = dir ? b1r : b1m;
    const float* B2  = dir ? b2r : b2m;
    f32x4 acc1[2][4];
    for (int a=0;a<2;a++)
      for (int b=0;b<4;b++){ f32x4 z = {0.f,0.f,0.f,0.f}; acc1[a][b]=z; }
    for (int ks=0; ks<10; ++ks){
      u16x8 bv[4], av[2];
      for (int nt=0; nt<4; ++nt)
        bv[nt] = W1T[(size_t)(wv*64 + nt*16 + l15)*40 + ks*4 + quad];
      int kb = ks*4 + quad;
      int kbm = dir ? (kb < 32 ? (kb ^ 16) : kb) : kb;
      for (int mt=0; mt<2; ++mt)
        av[mt] = Xs[kbm*32 + mt*16 + l15];
      for (int mt=0; mt<2; ++mt)
        for (int nt=0; nt<4; ++nt)
          acc1[mt][nt] = mfma16(av[mt], bv[nt], acc1[mt][nt]);
    }
    __syncthreads();
    for (int mt=0; mt<2; ++mt)
      for (int nt=0; nt<4; ++nt){
        int n = wv*64 + nt*16 + l15;
        float bias = B1[n];
        for (int r=0;r<4;r++){
          int mm = mt*16 + quad*4 + r;
          float v = fmaxf(acc1[mt][nt][r] + bias, 0.f);
          HsB[((n>>3)*32 + mm)*8 + (n&7)] = f2bf(v);
        }
      }
    __syncthreads();
    f32x4 acc2[2][2];
    for (int a=0;a<2;a++)
      for (int b=0;b<2;b++){ f32x4 z = {0.f,0.f,0.f,0.f}; acc2[a][b]=z; }
    for (int ks=0; ks<8; ++ks){
      u16x8 bv[2], av[2];
      for (int nt=0; nt<2; ++nt)
        bv[nt] = W2T[(size_t)(wv*32 + nt*16 + l15)*32 + ks*4 + quad];
      for (int mt=0; mt<2; ++mt)
        av[mt] = Hs[(ks*4 + quad)*32 + mt*16 + l15];
      for (int mt=0; mt<2; ++mt)
        for (int nt=0; nt<2; ++nt)
          acc2[mt][nt] = mfma16(av[mt], bv[nt], acc2[mt][nt]);
    }
    for (int mt=0; mt<2; ++mt)
      for (int nt=0; nt<2; ++nt){
        int n = wv*32 + nt*16 + l15;
        float bias = B2[n];
        for (int r=0;r<4;r++){
          int mm = mt*16 + quad*4 + r;
          int row = dir ? fromS[mm] : toS[mm];
          atomicAdd(agg + (size_t)row*128 + n, acc2[mt][nt][r] + bias);
        }
      }
  }
}

// ============================================================ message kernel v9: 128 edges/block, 1024 threads
// M-tile doubled again (confirmed weight-L2-amortization lever): per-ks bv
// reused across 8 MFMA. 16 waves; layer1 16-col slabs, layer2 8 slabs x 2
// M-halves. LDS ~149KB -> 1 block/CU (16 waves, same residency as 2x512).
__global__ void __launch_bounds__(1024, 4) k_msg9(
  const unsigned short* hbg, const void* efg,
  const int* from_idx, const int* to_idx, const int* ent,
  const unsigned short* w1tm, const unsigned short* w1tr,
  const unsigned short* w2tm, const unsigned short* w2tr,
  const unsigned short* wetp, const float* bef,
  const float* b1m, const float* b2m, const float* b1r, const float* b2r,
  float* agg, const int* flag)
{
  __shared__ __align__(16) unsigned short XsB[40*128*8];  // 81920 B
  __shared__ __align__(16) unsigned short HsB[32*128*8];  // 65536 B ; P (128x128 f32) aliases
  __shared__ int eS[128], fromS[128], toS[128];
  __shared__ int runBeg[129];
  __shared__ int nRunsS;
  int fl = *flag;
  u16x8* Xs = (u16x8*)XsB;
  u16x8* Hs = (u16x8*)HsB;
  const u16x8* hb8   = (const u16x8*)hbg;
  const u16x8* wetp8 = (const u16x8*)wetp;
  const u16x8* w1tm8 = (const u16x8*)w1tm;
  const u16x8* w1tr8 = (const u16x8*)w1tr;
  const u16x8* w2tm8 = (const u16x8*)w2tm;
  const u16x8* w2tr8 = (const u16x8*)w2tr;

  int tid = threadIdx.x;
  // XCD-chunked swizzle: XCD (= blockIdx%8) owns contiguous 1/8 of ent
  int cpx = (int)gridDim.x >> 3;
  int bb = ((int)blockIdx.x & 7) * cpx + ((int)blockIdx.x >> 3);
  int e0 = bb * 128;
  if (tid < 128){
    int e = ent[e0 + tid];          // coalesced (ent contiguous)
    eS[tid] = e;
    fromS[tid] = from_idx[e];
    toS[tid]   = to_idx[e];
  }
  __syncthreads();                  // B0: idx visible
  int w = tid>>6, lane = tid&63, quad = lane>>4, l15 = lane&15;
  u16x8 zero8 = {0,0,0,0,0,0,0,0};

  // run detection on sorted toS
  if (tid == 0){
    int nr = 0;
    for (int mm=0; mm<128; ++mm)
      if (mm==0 || toS[mm]!=toS[mm-1]) runBeg[nr++] = mm;
    runBeg[nr] = 128; nRunsS = nr;
  }
  // ---- stage h rows: Xs[kb][edge], kb 0..15 = h[from], 16..31 = h[to]
  {
    int edge = tid & 127, cg = tid >> 7;    // cg 0..7
    for (int j=0; j<4; ++j){
      int kb = cg + 8*j;                    // 0..31
      u16x8 v = (kb < 16) ? hb8[(size_t)fromS[edge]*16 + kb]
                          : hb8[(size_t)toS[edge]*16 + (kb-16)];
      Xs[kb*128 + edge] = v;
    }
  }
  // ---- fused edge-encode -> Xs rows 32..39 (4 M-groups x 4 N-slabs)
  {
    int wm = w >> 2, wn = w & 3;
    f32x4 accE[2];
    for (int a=0;a<2;a++){ f32x4 z = {0.f,0.f,0.f,0.f}; accE[a]=z; }
    u16x8 bvE = wetp8[(size_t)(wn*16 + l15)*4 + quad];
    for (int mt=0; mt<2; ++mt){
      u16x8 avE = zero8;
      if (quad < 2){
        int e = eS[wm*32 + mt*16 + l15];
        if (fl){
          avE = ((const u16x8*)efg)[(size_t)e*2 + quad];
        } else {
          const float* ep = (const float*)efg + (size_t)e*16 + quad*8;
          u16x8 v;
          for (int j=0;j<8;j++) v[j] = f2bf(ep[j]);
          avE = v;
        }
      }
      accE[mt] = mfma16(avE, bvE, accE[mt]);
    }
    int n = wn*16 + l15;
    float bias = bef[n];
    for (int mt=0; mt<2; ++mt)
      for (int r=0;r<4;r++){
        int me = wm*32 + mt*16 + quad*4 + r;
        XsB[((32 + (n>>3))*128 + me)*8 + (n&7)] = f2bf(accE[mt][r] + bias);
      }
  }
  __syncthreads();                  // B1: Xs + runs ready

  for (int dir=0; dir<2; ++dir){
    const u16x8* W1T = dir ? w1tr8 : w1tm8;
    const u16x8* W2T = dir ? w2tr8 : w2tm8;
    const float* B1  = dir ? b1r : b1m;
    // ---- layer 1: X(128x320)@W1(320x256); wave -> 16-col slab, M=128
    f32x4 acc1[8];
    for (int a=0;a<8;a++){ f32x4 z = {0.f,0.f,0.f,0.f}; acc1[a]=z; }
    int n1 = w*16 + l15;
    for (int ks=0; ks<10; ++ks){
      u16x8 bv1 = W1T[(size_t)n1*40 + ks*4 + quad];
      int kb = ks*4 + quad;
      int kbm = dir ? (kb < 32 ? (kb ^ 16) : kb) : kb;   // dir1: [dst,src,e]
      u16x8 av[8];
      for (int mt=0; mt<8; ++mt)
        av[mt] = Xs[kbm*128 + mt*16 + l15];
      for (int mt=0; mt<8; ++mt)
        acc1[mt] = mfma16(av[mt], bv1, acc1[mt]);
    }
    if (dir == 1) __syncthreads();   // merge reads of P done before Hs overwrite
    {
      float bias1 = B1[n1];
      for (int mt=0; mt<8; ++mt)
        for (int r=0;r<4;r++){
          int mm = mt*16 + quad*4 + r;
          float v = fmaxf(acc1[mt][r] + bias1, 0.f);
          HsB[((n1>>3)*128 + mm)*8 + (n1&7)] = f2bf(v);
        }
    }
    __syncthreads();                 // Hs ready
    // ---- layer 2: H(128x256)@W2(256x128); 8 N-slabs x 2 M-halves
    int wm2 = w >> 3, wn2 = w & 7;
    int n2 = wn2*16 + l15;
    f32x4 acc2[4];
    for (int a=0;a<4;a++){ f32x4 z = {0.f,0.f,0.f,0.f}; acc2[a]=z; }
    for (int ks=0; ks<8; ++ks){
      u16x8 bv2 = W2T[(size_t)n2*32 + ks*4 + quad];
      u16x8 av[4];
      for (int mt=0; mt<4; ++mt)
        av[mt] = Hs[(ks*4 + quad)*128 + wm2*64 + mt*16 + l15];
      for (int mt=0; mt<4; ++mt)
        acc2[mt] = mfma16(av[mt], bv2, acc2[mt]);
    }
    if (dir == 0){
      __syncthreads();               // Hs reads done -> P may overwrite
      float* P = (float*)HsB;        // 128x128 f32 = 65536B exactly
      float bias = b2m[n2];
      for (int mt=0; mt<4; ++mt)
        for (int r=0;r<4;r++){
          int mm = wm2*64 + mt*16 + quad*4 + r;
          P[mm*128 + n2] = acc2[mt][r] + bias;
        }
      __syncthreads();               // P complete
      // merge runs + one atomic per (run,col)
      int col = tid & 127, grp = tid >> 7;   // 8 groups
      int nr = nRunsS;
      for (int k = grp; k < nr; k += 8){
        int r0 = runBeg[k], r1 = runBeg[k+1];
        float s = 0.f;
        for (int mm = r0; mm < r1; ++mm) s += P[mm*128 + col];
        atomicAdd(agg + (size_t)toS[r0]*128 + col, s);
      }
    } else {
      // dir1: scatter to agg[from]
      float bias = b2r[n2];
      for (int mt=0; mt<4; ++mt)
        for (int r=0;r<4;r++){
          int mm = wm2*64 + mt*16 + quad*4 + r;
          atomicAdd(agg + (size_t)fromS[mm]*128 + n2, acc2[mt][r] + bias);
        }
    }
  }
}

// ============================================================ node update v2: 64 nodes/block, 512 threads
// Same weight-amortization lever: W1u/W2u L2 reads halved per node.
__global__ void __launch_bounds__(512, 4) k_upd(
  const float* agg, const unsigned short* hbg,
  const unsigned short* w1tu, const unsigned short* w2tu,
  const float* b1u, const float* b2u,
  unsigned short* hb, unsigned short* hl, int has_hl)
{
  __shared__ __align__(16) unsigned short XsB[32*64*8];   // 32768 B
  __shared__ __align__(16) unsigned short HsB[32*64*8];   // 32768 B
  u16x8* Xs = (u16x8*)XsB;
  u16x8* Hs = (u16x8*)HsB;
  const u16x8* hb8   = (const u16x8*)hbg;
  const u16x8* w1tu8 = (const u16x8*)w1tu;
  const u16x8* w2tu8 = (const u16x8*)w2tu;
  int tid = threadIdx.x;
  int n0 = blockIdx.x*64;
  {
    int node = tid & 63, cg = tid >> 6;     // cg 0..7
    for (int j=0; j<4; ++j){
      int kb = cg + 8*j;                    // 0..31
      u16x8 v;
      if (kb < 16){
        const float* ap = agg + (size_t)(n0+node)*128 + kb*8;
        for (int t=0;t<8;t++) v[t] = f2bf(ap[t]);
      } else {
        v = hb8[(size_t)(n0+node)*16 + (kb-16)];
      }
      Xs[kb*64 + node] = v;
    }
  }
  __syncthreads();
  int w = tid>>6, lane = tid&63, quad = lane>>4, l15 = lane&15;
  // layer1: X(64x256)@W1u(256x256); wave -> 32-col slab
  f32x4 acc1[4][2];
  for (int a=0;a<4;a++)
    for (int b=0;b<2;b++){ f32x4 z = {0.f,0.f,0.f,0.f}; acc1[a][b]=z; }
  for (int ks=0; ks<8; ++ks){
    u16x8 bv[2], av[4];
    for (int nt=0; nt<2; ++nt)
      bv[nt] = w1tu8[(size_t)(w*32 + nt*16 + l15)*32 + ks*4 + quad];
    for (int mt=0; mt<4; ++mt)
      av[mt] = Xs[(ks*4 + quad)*64 + mt*16 + l15];
    for (int mt=0; mt<4; ++mt)
      for (int nt=0; nt<2; ++nt)
        acc1[mt][nt] = mfma16(av[mt], bv[nt], acc1[mt][nt]);
  }
  __syncthreads();
  for (int mt=0; mt<4; ++mt)
    for (int nt=0; nt<2; ++nt){
      int n = w*32 + nt*16 + l15;
      float bias = b1u[n];
      for (int r=0;r<4;r++){
        int mm = mt*16 + quad*4 + r;
        float v = fmaxf(acc1[mt][nt][r] + bias, 0.f);
        HsB[((n>>3)*64 + mm)*8 + (n&7)] = f2bf(v);
      }
    }
  __syncthreads();
  // layer2: H(64x256)@W2u(256x128); wave -> 16-col slab
  f32x4 acc2[4];
  for (int a=0;a<4;a++){ f32x4 z = {0.f,0.f,0.f,0.f}; acc2[a]=z; }
  int n2 = w*16 + l15;
  for (int ks=0; ks<8; ++ks){
    u16x8 bv2 = w2tu8[(size_t)n2*32 + ks*4 + quad];
    u16x8 av[4];
    for (int mt=0; mt<4; ++mt)
      av[mt] = Hs[(ks*4 + quad)*64 + mt*16 + l15];
    for (int mt=0; mt<4; ++mt)
      acc2[mt] = mfma16(av[mt], bv2, acc2[mt]);
  }
  float bias = b2u[n2];
  for (int mt=0; mt<4; ++mt)
    for (int r=0;r<4;r++){
      int mm = mt*16 + quad*4 + r;
      size_t idx = (size_t)(n0+mm)*128 + n2;
      float base = bf2f(hb[idx]);
      if (has_hl) base += bf2f(hl[idx]);
      float nv = base + acc2[mt][r] + bias;
      unsigned short hi = f2bf(nv);
      hb[idx] = hi;
      if (has_hl) hl[idx] = f2bf(nv - bf2f(hi));
    }
}

// ============================================================ t-MLP — unchanged
__global__ void __launch_bounds__(256) k_tmlp(
  const unsigned short* hb, const unsigned short* hl, int has_hl,
  const float* fc1f, const float* fc2f,
  const float* fc1b, const float* fc2b, unsigned short* Th, unsigned short* Tl)
{
  __shared__ float Xs[16][128];
  __shared__ float Hsm[16][128];
  int tid = threadIdx.x, wv = tid>>6, lane = tid&63;
  int nodeBase = blockIdx.x*16 + wv*4;
  for (int i=0;i<4;i++){
    size_t base = (size_t)(nodeBase+i)*128 + lane*2;
    float x0 = bf2f(hb[base]), x1 = bf2f(hb[base+1]);
    if (has_hl){ x0 += bf2f(hl[base]); x1 += bf2f(hl[base+1]); }
    Xs[wv*4+i][lane*2] = x0; Xs[wv*4+i][lane*2+1] = x1;
  }
  __syncthreads();
  float a0[4], a1[4];
  for (int i=0;i<4;i++){ a0[i] = fc1b[lane*2]; a1[i] = fc1b[lane*2+1]; }
  for (int k=0;k<128;k++){
    f32x2 w = *(const f32x2*)&fc1f[k*128 + lane*2];
    for (int i=0;i<4;i++){ float x = Xs[wv*4+i][k]; a0[i] += x*w[0]; a1[i] += x*w[1]; }
  }
  for (int i=0;i<4;i++){
    Hsm[wv*4+i][lane*2]   = fmaxf(a0[i], 0.f);
    Hsm[wv*4+i][lane*2+1] = fmaxf(a1[i], 0.f);
  }
  __syncthreads();
  for (int i=0;i<4;i++){ a0[i] = fc2b[lane*2]; a1[i] = fc2b[lane*2+1]; }
  for (int k=0;k<128;k++){
    f32x2 w = *(const f32x2*)&fc2f[k*128 + lane*2];
    for (int i=0;i<4;i++){ float x = Hsm[wv*4+i][k]; a0[i] += x*w[0]; a1[i] += x*w[1]; }
  }
  for (int i=0;i<4;i++){
    size_t idx = (size_t)(nodeBase+i)*128 + lane*2;
    float t0 = a0[i], t1 = a1[i];
    unsigned short h0 = f2bf(t0), h1 = f2bf(t1);
    Th[idx] = h0; Th[idx+1] = h1;
    Tl[idx]   = f2bf(t0 - bf2f(h0));
    Tl[idx+1] = f2bf(t1 - bf2f(h1));
  }
}

// ============================================================ per-pair — unchanged
__global__ void __launch_bounds__(256) k_pair(
  const unsigned short* Th, const unsigned short* Tl,
  const unsigned short* hb, const unsigned short* hl, int has_hl,
  void* outv, const int* flag)
{
  __shared__ float la[8448];
  __shared__ float red[4];
  const u16x8* th8 = (const u16x8*)Th;
  const u16x8* tl8 = (const u16x8*)Tl;
  int b = blockIdx.x;
  int even = ((b & 1) == 0);
  int qs = even ? 128 : 64;
  int cs = 192 - qs;
  int nr = even ? 128 : 65;
  int nc = even ? 65 : 128;
  int st = nc + 1;
  int q0 = 192*b, c0 = q0 + qs;
  int tid = threadIdx.x, wv = tid>>6, lane = tid&63, quad = lane>>4, l15 = lane&15;
  u16x8 zero8 = {0,0,0,0,0,0,0,0};

  f32x4 acc[2][8];
  for (int a=0;a<2;a++)
    for (int c=0;c<8;c++){ f32x4 z = {0.f,0.f,0.f,0.f}; acc[a][c]=z; }
  for (int pass=0; pass<3; ++pass){
    const u16x8* A  = (pass==2) ? tl8 : th8;
    const u16x8* Bm = (pass==1) ? tl8 : th8;
    for (int ks=0; ks<4; ++ks){
      u16x8 av[2], bv[8];
      for (int mt=0; mt<2; ++mt){
        int q = wv*32 + mt*16 + l15;
        av[mt] = (q < qs) ? A[(size_t)(q0+q)*16 + ks*4 + quad] : zero8;
      }
      for (int nt=0; nt<8; ++nt){
        int c = nt*16 + l15;
        bv[nt] = (c < cs) ? Bm[(size_t)(c0+c)*16 + ks*4 + quad] : zero8;
      }
      for (int mt=0; mt<2; ++mt)
        for (int nt=0; nt<8; ++nt)
          acc[mt][nt] = mfma16(av[mt], bv[nt], acc[mt][nt]);
    }
  }
  for (int mt=0; mt<2; ++mt)
    for (int nt=0; nt<8; ++nt)
      for (int r=0;r<4;r++){
        int q = wv*32 + mt*16 + quad*4 + r;
        int c = nt*16 + l15;
        if (q < nr && c < nc) la[q*st + c] = acc[mt][nt][r] * 10.0f;
      }
  __syncthreads();

  for (int it=0; it<20; ++it){
    if (tid < nr){
      float* row = &la[tid*st];
      float mx = -1e30f;
      for (int c=0;c<nc;c++) mx = fmaxf(mx, row[c]);
      float s = 0.f, last = 0.f;
      for (int c=0;c<nc;c++){ float e = __expf(row[c]-mx); s += e; last = e; }
      if (even) s += 63.f * last;
      float l = mx + __logf(s);
      for (int c=0;c<nc;c++) row[c] -= l;
    }
    __syncthreads();
    if (tid < nc){
      int c = tid;
      float mx = -1e30f;
      for (int r=0;r<nr;r++) mx = fmaxf(mx, la[r*st + c]);
      float s = 0.f, last = 0.f;
      for (int r=0;r<nr;r++){ float e = __expf(la[r*st + c]-mx); s += e; last = e; }
      if (!even) s += 63.f * last;
      float l = mx + __logf(s);
      for (int r=0;r<nr;r++) la[r*st + c] -= l;
    }
    __syncthreads();
  }
  for (int i = tid; i < 8448; i += 256) la[i] = __expf(la[i]);
  __syncthreads();

  int d = tid & 127, qg = tid >> 7;
  int nsweep = (nr + 15) >> 4;
  float partial = 0.f;
  for (int sweep=0; sweep<nsweep; ++sweep){
    int qb = sweep*16 + qg*8;
    float acc2[8];
    for (int j=0;j<8;j++) acc2[j] = 0.f;
    for (int c=0; c<cs; ++c){
      size_t si = (size_t)(c0+c)*128 + d;
      float s = bf2f(hb[si]);
      if (has_hl) s += bf2f(hl[si]);
      for (int j=0;j<8;j++){
        int r = qb + j;
        if (r < nr) acc2[j] += la[r*st + c] * s;
      }
    }
    for (int j=0;j<8;j++){
      int r = qb + j;
      if (r < nr){
        float w = (!even && r == 64) ? 64.f : 1.f;
        float sq = 0.f;
        if (r < qs){
          size_t si = (size_t)(q0+r)*128 + d;
          sq = bf2f(hb[si]);
          if (has_hl) sq += bf2f(hl[si]);
        }
        partial += w * fmaxf(sq - acc2[j], 0.f);
      }
    }
  }
  for (int off=32; off>0; off>>=1) partial += __shfl_down(partial, off, 64);
  if (lane == 0) red[wv] = partial;
  __syncthreads();
  if (tid == 0){
    float tot = red[0] + red[1] + red[2] + red[3];
    if (*flag) ((unsigned short*)outv)[b] = f2bf(-tot);
    else       ((float*)outv)[b] = -tot;
  }
}

// ============================================================ host
extern "C" void kernel_launch(void* const* d_in, const int* in_sizes, int n_in,
                              void* d_out, int out_size, void* d_ws, size_t ws_size,
                              hipStream_t stream)
{
  if (ws_size < WS_MINI){
    k_sent<<<2, 256, 0, stream>>>((float*)d_out);
    return;
  }
  int has_hl = 0, use_s9 = 0;
  size_t off_csr = 0;
  if (ws_size >= WS_FULL_G){ has_hl = 1; use_s9 = 1; off_csr = WS_FULL; }
  else if (ws_size >= WS_FULL){ has_hl = 1; use_s9 = 0; }
  else if (ws_size >= WS_MINI_G){ has_hl = 0; use_s9 = 1; off_csr = WS_MINI; }

  const int* from_idx = (const int*)d_in[22];
  const int* to_idx   = (const int*)d_in[23];

  char* wsb = (char*)d_ws;
  unsigned short* hb  = (unsigned short*)(wsb + OFF_HB);
  unsigned short* hl  = (unsigned short*)(wsb + OFF_HL);
  float* agg          = (float*)(wsb + OFF_AGG);
  unsigned short* Th  = (unsigned short*)(wsb + OFF_TH);
  unsigned short* Tl  = (unsigned short*)(wsb + OFF_TL);
  int* flag           = (int*)(wsb + OFF_W + WO_FLAG);

  const unsigned short* w1tm = (const unsigned short*)(wsb + OFF_W + WO_W1TM);
  const unsigned short* w1tr = (const unsigned short*)(wsb + OFF_W + WO_W1TR);
  const unsigned short* w2tm = (const unsigned short*)(wsb + OFF_W + WO_W2TM);
  const unsigned short* w2tr = (const unsigned short*)(wsb + OFF_W + WO_W2TR);
  const unsigned short* w1tu = (const unsigned short*)(wsb + OFF_W + WO_W1TU);
  const unsigned short* w2tu = (const unsigned short*)(wsb + OFF_W + WO_W2TU);
  const unsigned short* wnt  = (const unsigned short*)(wsb + OFF_W + WO_WNT);
  const unsigned short* wetp = (const unsigned short*)(wsb + OFF_W + WO_WETP);
  const float* fc1f  = (const float*)(wsb + OFF_W + WO_FC1F);
  const float* fc2f  = (const float*)(wsb + OFF_W + WO_FC2F);
  const float* bnf   = (const float*)(wsb + OFF_W + WO_BNF);
  const float* bef   = (const float*)(wsb + OFF_W + WO_BEF);
  const float* b1m   = (const float*)(wsb + OFF_W + WO_B1M);
  const float* b2m   = (const float*)(wsb + OFF_W + WO_B2M);
  const float* b1r   = (const float*)(wsb + OFF_W + WO_B1R);
  const float* b2r   = (const float*)(wsb + OFF_W + WO_B2R);
  const float* b1u   = (const float*)(wsb + OFF_W + WO_B1U);
  const float* b2u   = (const float*)(wsb + OFF_W + WO_B2U);
  const float* f1b   = (const float*)(wsb + OFF_W + WO_FC1B);
  const float* f2b   = (const float*)(wsb + OFF_W + WO_FC2B);

  int* offs0 = (int*)(wsb + off_csr);
  int* offs1 = offs0 + (NN + 1);
  int* cur0  = offs1 + (NN + 1);
  int* cur1  = cur0 + NN;
  int* ent0  = cur1 + NN;
  int* ent1  = ent0 + NE;
  int* csum  = ent1 + NE;

  k_dtype<<<1, 64, 0, stream>>>((const unsigned short*)d_in[0], flag);

  k_canary<<<2, 256, 0, stream>>>(d_out, flag);

  k_prep<<<1439, 256, 0, stream>>>(
    d_in[2],  d_in[3],  d_in[4],  d_in[5],
    d_in[6],  d_in[7],  d_in[8],  d_in[9],
    d_in[10], d_in[11], d_in[12], d_in[13],
    d_in[14], d_in[15], d_in[16], d_in[17],
    d_in[18], d_in[19], d_in[20], d_in[21],
    wsb);

  if (use_s9){
    k_csr_zero <<<NN/256, 256, 0, stream>>>(cur0, cur1);
    k_csr_count<<<NE/256, 256, 0, stream>>>(from_idx, to_idx, cur0, cur1);
    k_scan1    <<<2*SCAN_CHUNKS, 256, 0, stream>>>(cur0, cur1, csum);
    k_scan2    <<<1, 128, 0, stream>>>(csum, offs0, offs1);
    k_scan3    <<<2*SCAN_CHUNKS, 256, 0, stream>>>(cur0, cur1, csum, offs0, offs1);
    k_csr_fill <<<NE/256, 256, 0, stream>>>(from_idx, to_idx, cur0, cur1, ent0, ent1);
  }

  k_enc_node<<<NN/64, 256, 0, stream>>>(d_in[0], wnt, bnf, hb, hl, has_hl, flag);

  for (int r=0; r<5; ++r){
    k_zero<<<3072, 256, 0, stream>>>(agg);
    if (use_s9){
      k_msg9<<<NE/128, 1024, 0, stream>>>(hb, d_in[1],
          from_idx, to_idx, ent0, w1tm, w1tr, w2tm, w2tr, wetp, bef,
          b1m, b2m, b1r, b2r, agg, flag);
    } else {
      k_msg<<<NE/32, 256, 0, stream>>>(hb, d_in[1],
          from_idx, to_idx, w1tm, w1tr, w2tm, w2tr, wetp, bef,
          b1m, b2m, b1r, b2r, agg, flag);
    }
    k_upd<<<NN/64, 512, 0, stream>>>(agg, hb, w1tu, w2tu, b1u, b2u, hb, hl, has_hl);
  }

  k_tmlp<<<NN/16, 256, 0, stream>>>(hb, hl, has_hl, fc1f, fc2f, f1b, f2b, Th, Tl);
  k_pair<<<NB, 256, 0, stream>>>(Th, Tl, hb, hl, has_hl, d_out, flag);
}

// Round 8
// 5815.895 us; speedup vs baseline: 1.0324x; 1.0324x over previous
//
#include <hip/hip_runtime.h>

using bf16x8 = __attribute__((ext_vector_type(8))) __bf16;
using u16x8  = __attribute__((ext_vector_type(8))) unsigned short;
using f32x4  = __attribute__((ext_vector_type(4))) float;
using f32x2  = __attribute__((ext_vector_type(2))) float;

#define DEV static __device__ __forceinline__

constexpr int NN = 98304;     // total nodes  (512 pairs * 192)
constexpr int NE = 786432;    // total edges  (8 * NN)
constexpr int NB = 512;       // pairs

// ---------------- workspace layout (bytes) ----------------
constexpr size_t OFF_HB  = 0;                                  // hb : NN*128 bf16 (25.2MB)
constexpr size_t OFF_AGG = OFF_HB + (size_t)NN*128*2;          // agg: NN*128 f32  (50.3MB)
constexpr size_t OFF_TH  = OFF_AGG;                            // Th aliases agg[0:25.2MB]
constexpr size_t OFF_TL  = OFF_AGG + (size_t)NN*128*2;         // Tl aliases agg[25.2:50.3MB]
constexpr size_t OFF_W   = OFF_AGG + (size_t)NN*128*4;         // weight area

constexpr size_t WO_W1TM = 0;                                  // [256][320] bf16
constexpr size_t WO_W1TR = WO_W1TM + (size_t)81920*2;
constexpr size_t WO_W2TM = WO_W1TR + (size_t)81920*2;          // [128][256] bf16
constexpr size_t WO_W2TR = WO_W2TM + (size_t)32768*2;
constexpr size_t WO_W1TU = WO_W2TR + (size_t)32768*2;          // [256][256] bf16
constexpr size_t WO_W2TU = WO_W1TU + (size_t)65536*2;          // [128][256] bf16
constexpr size_t WO_WNT  = WO_W2TU + (size_t)32768*2;          // [128][32] bf16
constexpr size_t WO_WETP = WO_WNT  + (size_t)4096*2;           // [64][32] bf16 (k>=16 zero)
constexpr size_t WO_FC1F = WO_WETP + (size_t)2048*2;           // [128][128] f32
constexpr size_t WO_FC2F = WO_FC1F + (size_t)16384*4;
constexpr size_t WO_BNF  = WO_FC2F + (size_t)16384*4;          // biases f32
constexpr size_t WO_BEF  = WO_BNF + 128*4;
constexpr size_t WO_B1M  = WO_BEF + 64*4;
constexpr size_t WO_B2M  = WO_B1M + 256*4;
constexpr size_t WO_B1R  = WO_B2M + 128*4;
constexpr size_t WO_B2R  = WO_B1R + 256*4;
constexpr size_t WO_B1U  = WO_B2R + 128*4;
constexpr size_t WO_B2U  = WO_B1U + 256*4;
constexpr size_t WO_FC1B = WO_B2U + 128*4;
constexpr size_t WO_FC2B = WO_FC1B + 128*4;
constexpr size_t WO_FLAG = WO_FC2B + 128*4;                    // int dtype flag
constexpr size_t WO_END  = WO_FLAG + 16;

constexpr size_t OFF_HL  = OFF_W + WO_END;                     // hl : NN*128 bf16 (full only)
constexpr size_t WS_MINI = OFF_HL;                             // ~76.3 MB
constexpr size_t WS_FULL = OFF_HL + (size_t)NN*128*2;          // ~101.5 MB

// ---------------- CSR region (appended; only if ws allows) ----------------
constexpr int    SCAN_CHUNKS= NN/256;                          // 384
constexpr size_t CSR_INTS   = (size_t)2*(NN+1) + (size_t)2*NN + (size_t)2*NE + 768;
constexpr size_t CSR_BYTES  = CSR_INTS*4;                      // ~7.5 MB
constexpr size_t WS_FULL_G  = WS_FULL + CSR_BYTES;             // ~109.3 MB (confirmed avail)
constexpr size_t WS_MINI_G  = WS_MINI + CSR_BYTES;             // ~84.2 MB

DEV unsigned short f2bf(float f){
  unsigned u = __float_as_uint(f);
  u += 0x7fffu + ((u >> 16) & 1u);          // RNE
  return (unsigned short)(u >> 16);
}
DEV float bf2f(unsigned short s){ return __uint_as_float(((unsigned)s) << 16); }

DEV unsigned short ldbf(const void* p, size_t i, int fl){
  return fl ? ((const unsigned short*)p)[i] : f2bf(((const float*)p)[i]);
}
DEV float ldf(const void* p, size_t i, int fl){
  return fl ? bf2f(((const unsigned short*)p)[i]) : ((const float*)p)[i];
}

DEV f32x4 mfma16(u16x8 a, u16x8 b, f32x4 c){
  bf16x8 A, B;
  __builtin_memcpy(&A, &a, 16);
  __builtin_memcpy(&B, &b, 16);
  return __builtin_amdgcn_mfma_f32_16x16x32_bf16(A, B, c, 0, 0, 0);
}

// ============================================================ dtype probe
__global__ void k_dtype(const unsigned short* nf_u16, int* flag){
  if (threadIdx.x != 0 || blockIdx.x != 0) return;
  int sane = 0;
  for (int i = 0; i < 64; ++i){
    unsigned short v = nf_u16[2*i];
    int e = (v >> 7) & 0xFF;
    if (e >= 0x70 && e <= 0x8E) sane++;
  }
  *flag = (sane >= 32) ? 1 : 0;
}

// ============================================================ ws-too-small sentinel
__global__ void k_sent(float* out){
  int i = blockIdx.x*256 + threadIdx.x;
  if (i < NB) out[i] = 10000.f;
}

// ============================================================ canary
__global__ void k_canary(void* out, const int* flag){
  int i = blockIdx.x*256 + threadIdx.x;
  if (i < NB){
    if (*flag) ((unsigned short*)out)[i] = (unsigned short)0x4580u;
    else       ((float*)out)[i] = 4096.f;
  }
}

// ============================================================ zero agg (round-0 only; later rounds fused into k_upd)
__global__ void k_zero(float* agg){
  f32x4* p = (f32x4*)agg;
  int gtid = blockIdx.x*256 + threadIdx.x;
  for (int i = gtid; i < NN*128/4; i += 786432){
    f32x4 z = {0.f, 0.f, 0.f, 0.f};
    p[i] = z;
  }
}

// ============================================================ prep: transpose/convert weights
__global__ void k_prep(
  const void* enc_node_w, const void* enc_node_b,
  const void* enc_edge_w, const void* enc_edge_b,
  const void* msg_w1, const void* msg_b1,
  const void* msg_w2, const void* msg_b2,
  const void* rmsg_w1, const void* rmsg_b1,
  const void* rmsg_w2, const void* rmsg_b2,
  const void* upd_w1, const void* upd_b1,
  const void* upd_w2, const void* upd_b2,
  const void* fc1_w, const void* fc1_b,
  const void* fc2_w, const void* fc2_b,
  char* wsb)
{
  int fl = *(const int*)(wsb + OFF_W + WO_FLAG);
  int i = blockIdx.x*256 + threadIdx.x;
  unsigned short* W1Tm = (unsigned short*)(wsb + OFF_W + WO_W1TM);
  unsigned short* W1Tr = (unsigned short*)(wsb + OFF_W + WO_W1TR);
  unsigned short* W2Tm = (unsigned short*)(wsb + OFF_W + WO_W2TM);
  unsigned short* W2Tr = (unsigned short*)(wsb + OFF_W + WO_W2TR);
  unsigned short* W1Tu = (unsigned short*)(wsb + OFF_W + WO_W1TU);
  unsigned short* W2Tu = (unsigned short*)(wsb + OFF_W + WO_W2TU);
  unsigned short* WnT  = (unsigned short*)(wsb + OFF_W + WO_WNT);
  unsigned short* WeTp = (unsigned short*)(wsb + OFF_W + WO_WETP);
  float* fc1f = (float*)(wsb + OFF_W + WO_FC1F);
  float* fc2f = (float*)(wsb + OFF_W + WO_FC2F);
  float* bnf  = (float*)(wsb + OFF_W + WO_BNF);
  float* bef  = (float*)(wsb + OFF_W + WO_BEF);
  float* b1m  = (float*)(wsb + OFF_W + WO_B1M);
  float* b2m  = (float*)(wsb + OFF_W + WO_B2M);
  float* b1r  = (float*)(wsb + OFF_W + WO_B1R);
  float* b2r  = (float*)(wsb + OFF_W + WO_B2R);
  float* b1u  = (float*)(wsb + OFF_W + WO_B1U);
  float* b2u  = (float*)(wsb + OFF_W + WO_B2U);
  float* f1b  = (float*)(wsb + OFF_W + WO_FC1B);
  float* f2b  = (float*)(wsb + OFF_W + WO_FC2B);

  if (i < 81920){ W1Tm[i] = ldbf(msg_w1,  (size_t)(i%320)*256 + (i/320), fl); return; } i -= 81920;
  if (i < 81920){ W1Tr[i] = ldbf(rmsg_w1, (size_t)(i%320)*256 + (i/320), fl); return; } i -= 81920;
  if (i < 32768){ W2Tm[i] = ldbf(msg_w2,  (size_t)(i%256)*128 + (i/256), fl); return; } i -= 32768;
  if (i < 32768){ W2Tr[i] = ldbf(rmsg_w2, (size_t)(i%256)*128 + (i/256), fl); return; } i -= 32768;
  if (i < 65536){ W1Tu[i] = ldbf(upd_w1,  (size_t)(i%256)*256 + (i/256), fl); return; } i -= 65536;
  if (i < 32768){ W2Tu[i] = ldbf(upd_w2,  (size_t)(i%256)*128 + (i/256), fl); return; } i -= 32768;
  if (i <  4096){ WnT[i]  = ldbf(enc_node_w, (size_t)(i%32)*128 + (i/32), fl); return; } i -= 4096;
  if (i <  2048){ int k = i%32, n = i/32;
                  WeTp[i] = (k<16) ? ldbf(enc_edge_w, (size_t)k*64 + n, fl) : (unsigned short)0; return; } i -= 2048;
  if (i < 16384){ fc1f[i] = ldf(fc1_w, i, fl); return; } i -= 16384;
  if (i < 16384){ fc2f[i] = ldf(fc2_w, i, fl); return; } i -= 16384;
  if (i <   128){ bnf[i] = ldf(enc_node_b, i, fl); return; } i -= 128;
  if (i <    64){ bef[i] = ldf(enc_edge_b, i, fl); return; } i -= 64;
  if (i <   256){ b1m[i] = ldf(msg_b1, i, fl); return; } i -= 256;
  if (i <   128){ b2m[i] = ldf(msg_b2, i, fl); return; } i -= 128;
  if (i <   256){ b1r[i] = ldf(rmsg_b1, i, fl); return; } i -= 256;
  if (i <   128){ b2r[i] = ldf(rmsg_b2, i, fl); return; } i -= 128;
  if (i <   256){ b1u[i] = ldf(upd_b1, i, fl); return; } i -= 256;
  if (i <   128){ b2u[i] = ldf(upd_b2, i, fl); return; } i -= 128;
  if (i <   128){ f1b[i] = ldf(fc1_b, i, fl); return; } i -= 128;
  if (i <   128){ f2b[i] = ldf(fc2_b, i, fl); return; }
}

// ============================================================ CSR build (one-time per call)
__global__ void k_csr_zero(int* cur0, int* cur1){
  int i = blockIdx.x*256 + threadIdx.x;
  if (i < NN){ cur0[i] = 0; cur1[i] = 0; }
}
__global__ void k_csr_count(const int* from_idx, const int* to_idx, int* cur0, int* cur1){
  int e = blockIdx.x*256 + threadIdx.x;
  if (e < NE){
    atomicAdd(&cur0[to_idx[e]], 1);
    atomicAdd(&cur1[from_idx[e]], 1);
  }
}
__global__ void k_scan1(const int* cur0, const int* cur1, int* csum){
  __shared__ int red[256];
  int b = blockIdx.x, tid = threadIdx.x;
  const int* c = (b >= SCAN_CHUNKS) ? cur1 : cur0;
  int cb = (b >= SCAN_CHUNKS) ? (b - SCAN_CHUNKS) : b;
  red[tid] = c[cb*256 + tid];
  __syncthreads();
  for (int off = 128; off > 0; off >>= 1){
    if (tid < off) red[tid] += red[tid + off];
    __syncthreads();
  }
  if (tid == 0) csum[b] = red[0];
}
__global__ void k_scan2(int* csum, int* offs0, int* offs1){
  int wv = threadIdx.x >> 6, lane = threadIdx.x & 63;
  if (wv >= 2) return;
  int basei = wv * SCAN_CHUNKS;
  int carry = 0;
  for (int j = 0; j < SCAN_CHUNKS/64; ++j){
    int x = csum[basei + j*64 + lane];
    int s = x;
    for (int off = 1; off < 64; off <<= 1){
      int t = __shfl_up(s, off, 64);
      if (lane >= off) s += t;
    }
    csum[basei + j*64 + lane] = s - x + carry;   // exclusive
    carry += __shfl(s, 63, 64);
  }
  if (lane == 0){
    if (wv == 0) offs0[NN] = carry; else offs1[NN] = carry;
  }
}
__global__ void k_scan3(int* cur0, int* cur1, const int* csum, int* offs0, int* offs1){
  __shared__ int s[256];
  int b = blockIdx.x, tid = threadIdx.x;
  int dir = (b >= SCAN_CHUNKS) ? 1 : 0;
  int cb  = dir ? (b - SCAN_CHUNKS) : b;
  int* c    = dir ? cur1 : cur0;
  int* offs = dir ? offs1 : offs0;
  int v = c[cb*256 + tid];
  s[tid] = v;
  __syncthreads();
  for (int off = 1; off < 256; off <<= 1){
    int t = (tid >= off) ? s[tid - off] : 0;
    __syncthreads();
    s[tid] += t;
    __syncthreads();
  }
  int excl = s[tid] - v + csum[b];
  offs[cb*256 + tid] = excl;
  c[cb*256 + tid] = excl;          // cursor = start offset
}
__global__ void k_csr_fill(const int* from_idx, const int* to_idx,
                           int* cur0, int* cur1, int* ent0, int* ent1){
  int e = blockIdx.x*256 + threadIdx.x;
  if (e < NE){
    int p0 = atomicAdd(&cur0[to_idx[e]], 1);   ent0[p0] = e;
    int p1 = atomicAdd(&cur1[from_idx[e]], 1); ent1[p1] = e;
  }
}

// ============================================================ node encoder
__global__ void __launch_bounds__(256) k_enc_node(
  const void* nf, const unsigned short* wnt, const float* bnf,
  unsigned short* hb, unsigned short* hl, int has_hl, const int* flag)
{
  int fl = *flag;
  const u16x8* wnt8 = (const u16x8*)wnt;
  int tid = threadIdx.x, wv = tid>>6, lane = tid&63, quad = lane>>4, l15 = lane&15;
  int n0 = blockIdx.x*64;
  f32x4 acc[4][2];
  for (int a=0;a<4;a++){ f32x4 z = {0.f,0.f,0.f,0.f}; acc[a][0]=z; acc[a][1]=z; }
  u16x8 av[4], bv[2];
  if (fl){
    const u16x8* nf8 = (const u16x8*)nf;
    for (int mt=0; mt<4; ++mt) av[mt] = nf8[(size_t)(n0 + mt*16 + l15)*4 + quad];
  } else {
    const float* nff = (const float*)nf;
    for (int mt=0; mt<4; ++mt){
      const float* rp = nff + (size_t)(n0 + mt*16 + l15)*32 + quad*8;
      u16x8 v;
      for (int j=0;j<8;j++) v[j] = f2bf(rp[j]);
      av[mt] = v;
    }
  }
  for (int nt=0; nt<2; ++nt) bv[nt] = wnt8[(size_t)(wv*32 + nt*16 + l15)*4 + quad];
  for (int mt=0; mt<4; ++mt)
    for (int nt=0; nt<2; ++nt)
      acc[mt][nt] = mfma16(av[mt], bv[nt], acc[mt][nt]);
  for (int mt=0; mt<4; ++mt)
    for (int nt=0; nt<2; ++nt){
      int n = wv*32 + nt*16 + l15;
      float bias = bnf[n];
      for (int r=0;r<4;r++){
        int m = mt*16 + quad*4 + r;
        float v = acc[mt][nt][r] + bias;
        size_t idx = (size_t)(n0+m)*128 + n;
        unsigned short hi = f2bf(v);
        hb[idx] = hi;
        if (has_hl) hl[idx] = f2bf(v - bf2f(hi));
      }
    }
}

// ============================================================ message kernel (ATOMIC FALLBACK)
__global__ void __launch_bounds__(256) k_msg(
  const unsigned short* hbg, const void* efg,
  const int* from_idx, const int* to_idx,
  const unsigned short* w1tm, const unsigned short* w1tr,
  const unsigned short* w2tm, const unsigned short* w2tr,
  const unsigned short* wetp, const float* bef,
  const float* b1m, const float* b2m, const float* b1r, const float* b2r,
  float* agg, const int* flag)
{
  __shared__ __align__(16) unsigned short XsB[40*32*8];   // 20480 B
  __shared__ __align__(16) unsigned short HsB[32*32*8];   // 16384 B
  __shared__ int fromS[32], toS[32];
  int fl = *flag;
  u16x8* Xs = (u16x8*)XsB;
  u16x8* Hs = (u16x8*)HsB;
  const u16x8* hb8   = (const u16x8*)hbg;
  const u16x8* wetp8 = (const u16x8*)wetp;
  const u16x8* w1tm8 = (const u16x8*)w1tm;
  const u16x8* w1tr8 = (const u16x8*)w1tr;
  const u16x8* w2tm8 = (const u16x8*)w2tm;
  const u16x8* w2tr8 = (const u16x8*)w2tr;

  int tid = threadIdx.x;
  int e0 = blockIdx.x*32;
  if (tid < 32) fromS[tid] = from_idx[e0 + tid];
  else if (tid < 64) toS[tid-32] = to_idx[e0 + tid - 32];
  __syncthreads();
  int m = tid & 31, g = tid >> 5;
  int wv = tid>>6, lane = tid&63, quad = lane>>4, l15 = lane&15;
  u16x8 zero8 = {0,0,0,0,0,0,0,0};

  for (int j=0; j<4; ++j){
    int kb = g + 8*j;
    u16x8 v = (kb < 16) ? hb8[(size_t)fromS[m]*16 + kb]
                        : hb8[(size_t)toS[m]*16 + (kb-16)];
    Xs[kb*32 + m] = v;
  }
  {
    f32x4 accE[2];
    for (int a=0;a<2;a++){ f32x4 z = {0.f,0.f,0.f,0.f}; accE[a]=z; }
    u16x8 bvE = wetp8[(size_t)(wv*16 + l15)*4 + quad];
    for (int mt=0; mt<2; ++mt){
      u16x8 avE = zero8;
      if (quad < 2){
        if (fl){
          avE = ((const u16x8*)efg)[(size_t)(e0 + mt*16 + l15)*2 + quad];
        } else {
          const float* ep = (const float*)efg + (size_t)(e0 + mt*16 + l15)*16 + quad*8;
          u16x8 v;
          for (int j=0;j<8;j++) v[j] = f2bf(ep[j]);
          avE = v;
        }
      }
      accE[mt] = mfma16(avE, bvE, accE[mt]);
    }
    int n = wv*16 + l15;
    float bias = bef[n];
    for (int mt=0; mt<2; ++mt)
      for (int r=0;r<4;r++){
        int me = mt*16 + quad*4 + r;
        XsB[((32 + (n>>3))*32 + me)*8 + (n&7)] = f2bf(accE[mt][r] + bias);
      }
  }
  __syncthreads();

  for (int dir=0; dir<2; ++dir){
    const u16x8* W1T = dir ? w1tr8 : w1tm8;
    const u16x8* W2T = dir ? w2tr8 : w2tm8;
    const float* B1  = dir ? b1r : b1m;
    const float* B2  = dir ? b2r : b2m;
    f32x4 acc1[2][4];
    for (int a=0;a<2;a++)
      for (int b=0;b<4;b++){ f32x4 z = {0.f,0.f,0.f,0.f}; acc1[a][b]=z; }
    for (int ks=0; ks<10; ++ks){
      u16x8 bv[4], av[2];
      for (int nt=0; nt<4; ++nt)
        bv[nt] = W1T[(size_t)(wv*64 + nt*16 + l15)*40 + ks*4 + quad];
      int kb = ks*4 + quad;
      int kbm = dir ? (kb < 32 ? (kb ^ 16) : kb) : kb;
      for (int mt=0; mt<2; ++mt)
        av[mt] = Xs[kbm*32 + mt*16 + l15];
      for (int mt=0; mt<2; ++mt)
        for (int nt=0; nt<4; ++nt)
          acc1[mt][nt] = mfma16(av[mt], bv[nt], acc1[mt][nt]);
    }
    __syncthreads();
    for (int mt=0; mt<2; ++mt)
      for (int nt=0; nt<4; ++nt){
        int n = wv*64 + nt*16 + l15;
        float bias = B1[n];
        for (int r=0;r<4;r++){
          int mm = mt*16 + quad*4 + r;
          float v = fmaxf(acc1[mt][nt][r] + bias, 0.f);
          HsB[((n>>3)*32 + mm)*8 + (n&7)] = f2bf(v);
        }
      }
    __syncthreads();
    f32x4 acc2[2][2];
    for (int a=0;a<2;a++)
      for (int b=0;b<2;b++){ f32x4 z = {0.f,0.f,0.f,0.f}; acc2[a][b]=z; }
    for (int ks=0; ks<8; ++ks){
      u16x8 bv[2], av[2];
      for (int nt=0; nt<2; ++nt)
        bv[nt] = W2T[(size_t)(wv*32 + nt*16 + l15)*32 + ks*4 + quad];
      for (int mt=0; mt<2; ++mt)
        av[mt] = Hs[(ks*4 + quad)*32 + mt*16 + l15];
      for (int mt=0; mt<2; ++mt)
        for (int nt=0; nt<2; ++nt)
          acc2[mt][nt] = mfma16(av[mt], bv[nt], acc2[mt][nt]);
    }
    for (int mt=0; mt<2; ++mt)
      for (int nt=0; nt<2; ++nt){
        int n = wv*32 + nt*16 + l15;
        float bias = B2[n];
        for (int r=0;r<4;r++){
          int mm = mt*16 + quad*4 + r;
          int row = dir ? fromS[mm] : toS[mm];
          atomicAdd(agg + (size_t)row*128 + n, acc2[mt][nt][r] + bias);
        }
      }
  }
}

// ============================================================ message kernel v8: k_msg7 + weight-fragment prefetch
// 64 edges/block, 512 threads. L2-latency on bv loads hidden by double-buffer:
// load ks+1's W fragment while MFMA consumes ks's.
__global__ void __launch_bounds__(512, 4) k_msg8(
  const unsigned short* hbg, const void* efg,
  const int* from_idx, const int* to_idx, const int* ent,
  const unsigned short* w1tm, const unsigned short* w1tr,
  const unsigned short* w2tm, const unsigned short* w2tr,
  const unsigned short* wetp, const float* bef,
  const float* b1m, const float* b2m, const float* b1r, const float* b2r,
  float* agg, const int* flag)
{
  __shared__ __align__(16) unsigned short XsB[40*64*8];   // 40960 B
  __shared__ __align__(16) unsigned short HsB[32*64*8];   // 32768 B ; P (64x128 f32) aliases
  __shared__ int eS[64], fromS[64], toS[64];
  __shared__ int runBeg[65];
  __shared__ int nRunsS;
  int fl = *flag;
  u16x8* Xs = (u16x8*)XsB;
  u16x8* Hs = (u16x8*)HsB;
  const u16x8* hb8   = (const u16x8*)hbg;
  const u16x8* wetp8 = (const u16x8*)wetp;
  const u16x8* w1tm8 = (const u16x8*)w1tm;
  const u16x8* w1tr8 = (const u16x8*)w1tr;
  const u16x8* w2tm8 = (const u16x8*)w2tm;
  const u16x8* w2tr8 = (const u16x8*)w2tr;

  int tid = threadIdx.x;
  // XCD-chunked swizzle: XCD (= blockIdx%8) owns contiguous 1/8 of ent
  int cpx = (int)gridDim.x >> 3;
  int bb = ((int)blockIdx.x & 7) * cpx + ((int)blockIdx.x >> 3);
  int e0 = bb * 64;
  if (tid < 64){
    int e = ent[e0 + tid];          // coalesced (ent contiguous)
    eS[tid] = e;
    fromS[tid] = from_idx[e];
    toS[tid]   = to_idx[e];
  }
  __syncthreads();                  // B0: idx visible
  int w = tid>>6, lane = tid&63, quad = lane>>4, l15 = lane&15;
  u16x8 zero8 = {0,0,0,0,0,0,0,0};

  // run detection on sorted toS
  if (tid == 0){
    int nr = 0;
    for (int mm=0; mm<64; ++mm)
      if (mm==0 || toS[mm]!=toS[mm-1]) runBeg[nr++] = mm;
    runBeg[nr] = 64; nRunsS = nr;
  }
  // ---- stage h rows: Xs[kb][edge], kb 0..15 = h[from], 16..31 = h[to]
  {
    int edge = tid & 63, cg = tid >> 6;     // cg 0..7
    for (int j=0; j<4; ++j){
      int kb = cg + 8*j;                    // 0..31
      u16x8 v = (kb < 16) ? hb8[(size_t)fromS[edge]*16 + kb]
                          : hb8[(size_t)toS[edge]*16 + (kb-16)];
      Xs[kb*64 + edge] = v;
    }
  }
  // ---- fused edge-encode -> Xs rows 32..39
  {
    int wm = w >> 2, wn = w & 3;            // M-half, 16-col slab
    f32x4 accE[2];
    for (int a=0;a<2;a++){ f32x4 z = {0.f,0.f,0.f,0.f}; accE[a]=z; }
    u16x8 bvE = wetp8[(size_t)(wn*16 + l15)*4 + quad];
    for (int mt=0; mt<2; ++mt){
      u16x8 avE = zero8;
      if (quad < 2){
        int e = eS[wm*32 + mt*16 + l15];
        if (fl){
          avE = ((const u16x8*)efg)[(size_t)e*2 + quad];
        } else {
          const float* ep = (const float*)efg + (size_t)e*16 + quad*8;
          u16x8 v;
          for (int j=0;j<8;j++) v[j] = f2bf(ep[j]);
          avE = v;
        }
      }
      accE[mt] = mfma16(avE, bvE, accE[mt]);
    }
    int n = wn*16 + l15;
    float bias = bef[n];
    for (int mt=0; mt<2; ++mt)
      for (int r=0;r<4;r++){
        int me = wm*32 + mt*16 + quad*4 + r;
        XsB[((32 + (n>>3))*64 + me)*8 + (n&7)] = f2bf(accE[mt][r] + bias);
      }
  }
  __syncthreads();                  // B1: Xs + runs ready

  for (int dir=0; dir<2; ++dir){
    const u16x8* W1T = dir ? w1tr8 : w1tm8;
    const u16x8* W2T = dir ? w2tr8 : w2tm8;
    const float* B1  = dir ? b1r : b1m;
    // ---- layer 1: X(64x320)@W1(320x256); wave -> 32-col slab; bv double-buffered
    f32x4 acc1[4][2];
    for (int a=0;a<4;a++)
      for (int b=0;b<2;b++){ f32x4 z = {0.f,0.f,0.f,0.f}; acc1[a][b]=z; }
    u16x8 bvA[2], bvB[2];
    for (int nt=0; nt<2; ++nt)
      bvA[nt] = W1T[(size_t)(w*32 + nt*16 + l15)*40 + quad];          // ks=0
    for (int ks=0; ks<10; ++ks){
      if (ks < 9)
        for (int nt=0; nt<2; ++nt)
          bvB[nt] = W1T[(size_t)(w*32 + nt*16 + l15)*40 + (ks+1)*4 + quad];
      else { bvB[0] = bvA[0]; bvB[1] = bvA[1]; }
      int kb = ks*4 + quad;
      int kbm = dir ? (kb < 32 ? (kb ^ 16) : kb) : kb;   // dir1: [dst,src,e]
      u16x8 av[4];
      for (int mt=0; mt<4; ++mt)
        av[mt] = Xs[kbm*64 + mt*16 + l15];
      for (int mt=0; mt<4; ++mt)
        for (int nt=0; nt<2; ++nt)
          acc1[mt][nt] = mfma16(av[mt], bvA[nt], acc1[mt][nt]);
      bvA[0] = bvB[0]; bvA[1] = bvB[1];
    }
    if (dir == 1) __syncthreads();   // merge reads of P done before Hs overwrite
    for (int mt=0; mt<4; ++mt)
      for (int nt=0; nt<2; ++nt){
        int n = w*32 + nt*16 + l15;
        float bias = B1[n];
        for (int r=0;r<4;r++){
          int mm = mt*16 + quad*4 + r;
          float v = fmaxf(acc1[mt][nt][r] + bias, 0.f);
          HsB[((n>>3)*64 + mm)*8 + (n&7)] = f2bf(v);
        }
      }
    __syncthreads();                 // Hs ready
    // ---- layer 2: H(64x256)@W2(256x128); wave -> 16-col slab; bv double-buffered
    f32x4 acc2[4];
    for (int a=0;a<4;a++){ f32x4 z = {0.f,0.f,0.f,0.f}; acc2[a]=z; }
    int n2 = w*16 + l15;
    u16x8 bvC = W2T[(size_t)n2*32 + quad];                            // ks=0
    for (int ks=0; ks<8; ++ks){
      u16x8 bvN = bvC;
      if (ks < 7) bvN = W2T[(size_t)n2*32 + (ks+1)*4 + quad];
      u16x8 av[4];
      for (int mt=0; mt<4; ++mt)
        av[mt] = Hs[(ks*4 + quad)*64 + mt*16 + l15];
      for (int mt=0; mt<4; ++mt)
        acc2[mt] = mfma16(av[mt], bvC, acc2[mt]);
      bvC = bvN;
    }
    if (dir == 0){
      __syncthreads();               // Hs reads done -> P may overwrite
      float* P = (float*)HsB;        // 64x128 f32 = 32768B exactly
      float bias = b2m[n2];
      for (int mt=0; mt<4; ++mt)
        for (int r=0;r<4;r++){
          int mm = mt*16 + quad*4 + r;
          P[mm*128 + n2] = acc2[mt][r] + bias;
        }
      __syncthreads();               // P complete
      // merge runs + one atomic per (run,col)
      int col = tid & 127, grp = tid >> 7;   // 4 groups
      int nr = nRunsS;
      for (int k = grp; k < nr; k += 4){
        int r0 = runBeg[k], r1 = runBeg[k+1];
        float s = 0.f;
        for (int mm = r0; mm < r1; ++mm) s += P[mm*128 + col];
        atomicAdd(agg + (size_t)toS[r0]*128 + col, s);
      }
    } else {
      // dir1: scatter to agg[from]
      float bias = b2r[n2];
      for (int mt=0; mt<4; ++mt)
        for (int r=0;r<4;r++){
          int mm = mt*16 + quad*4 + r;
          atomicAdd(agg + (size_t)fromS[mm]*128 + n2, acc2[mt][r] + bias);
        }
    }
  }
}

// ============================================================ node update: 64 nodes/block, 512 threads
// + fused agg-zeroing for the NEXT round (replaces standalone k_zero)
// + bv prefetch (same L2-latency lever as k_msg8)
__global__ void __launch_bounds__(512, 4) k_upd(
  float* agg, const unsigned short* hbg,
  const unsigned short* w1tu, const unsigned short* w2tu,
  const float* b1u, const float* b2u,
  unsigned short* hb, unsigned short* hl, int has_hl)
{
  __shared__ __align__(16) unsigned short XsB[32*64*8];   // 32768 B
  __shared__ __align__(16) unsigned short HsB[32*64*8];   // 32768 B
  u16x8* Xs = (u16x8*)XsB;
  u16x8* Hs = (u16x8*)HsB;
  const u16x8* hb8   = (const u16x8*)hbg;
  const u16x8* w1tu8 = (const u16x8*)w1tu;
  const u16x8* w2tu8 = (const u16x8*)w2tu;
  int tid = threadIdx.x;
  int n0 = blockIdx.x*64;
  {
    int node = tid & 63, cg = tid >> 6;     // cg 0..7
    for (int j=0; j<4; ++j){
      int kb = cg + 8*j;                    // 0..31
      u16x8 v;
      if (kb < 16){
        const float* ap = agg + (size_t)(n0+node)*128 + kb*8;
        for (int t=0;t<8;t++) v[t] = f2bf(ap[t]);
      } else {
        v = hb8[(size_t)(n0+node)*16 + (kb-16)];
      }
      Xs[kb*64 + node] = v;
    }
  }
  __syncthreads();
  // fused zero of this block's agg rows (all staging reads done)
  {
    f32x4* ap4 = (f32x4*)(agg + (size_t)n0*128);
    f32x4 z = {0.f,0.f,0.f,0.f};
    for (int i = tid; i < 64*128/4; i += 512) ap4[i] = z;
  }
  int w = tid>>6, lane = tid&63, quad = lane>>4, l15 = lane&15;
  // layer1: X(64x256)@W1u(256x256); wave -> 32-col slab; bv prefetch
  f32x4 acc1[4][2];
  for (int a=0;a<4;a++)
    for (int b=0;b<2;b++){ f32x4 z = {0.f,0.f,0.f,0.f}; acc1[a][b]=z; }
  {
    u16x8 bvA[2], bvB[2];
    for (int nt=0; nt<2; ++nt)
      bvA[nt] = w1tu8[(size_t)(w*32 + nt*16 + l15)*32 + quad];
    for (int ks=0; ks<8; ++ks){
      if (ks < 7)
        for (int nt=0; nt<2; ++nt)
          bvB[nt] = w1tu8[(size_t)(w*32 + nt*16 + l15)*32 + (ks+1)*4 + quad];
      else { bvB[0] = bvA[0]; bvB[1] = bvA[1]; }
      u16x8 av[4];
      for (int mt=0; mt<4; ++mt)
        av[mt] = Xs[(ks*4 + quad)*64 + mt*16 + l15];
      for (int mt=0; mt<4; ++mt)
        for (int nt=0; nt<2; ++nt)
          acc1[mt][nt] = mfma16(av[mt], bvA[nt], acc1[mt][nt]);
      bvA[0] = bvB[0]; bvA[1] = bvB[1];
    }
  }
  __syncthreads();
  for (int mt=0; mt<4; ++mt)
    for (int nt=0; nt<2; ++nt){
      int n = w*32 + nt*16 + l15;
      float bias = b1u[n];
      for (int r=0;r<4;r++){
        int mm = mt*16 + quad*4 + r;
        float v = fmaxf(acc1[mt][nt][r] + bias, 0.f);
        HsB[((n>>3)*64 + mm)*8 + (n&7)] = f2bf(v);
      }
    }
  __syncthreads();
  // layer2: H(64x256)@W2u(256x128); wave -> 16-col slab; bv prefetch
  f32x4 acc2[4];
  for (int a=0;a<4;a++){ f32x4 z = {0.f,0.f,0.f,0.f}; acc2[a]=z; }
  int n2 = w*16 + l15;
  {
    u16x8 bvC = w2tu8[(size_t)n2*32 + quad];
    for (int ks=0; ks<8; ++ks){
      u16x8 bvN = bvC;
      if (ks < 7) bvN = w2tu8[(size_t)n2*32 + (ks+1)*4 + quad];
      u16x8 av[4];
      for (int mt=0; mt<4; ++mt)
        av[mt] = Hs[(ks*4 + quad)*64 + mt*16 + l15];
      for (int mt=0; mt<4; ++mt)
        acc2[mt] = mfma16(av[mt], bvC, acc2[mt]);
      bvC = bvN;
    }
  }
  float bias = b2u[n2];
  for (int mt=0; mt<4; ++mt)
    for (int r=0;r<4;r++){
      int mm = mt*16 + quad*4 + r;
      size_t idx = (size_t)(n0+mm)*128 + n2;
      float base = bf2f(hb[idx]);
      if (has_hl) base += bf2f(hl[idx]);
      float nv = base + acc2[mt][r] + bias;
      unsigned short hi = f2bf(nv);
      hb[idx] = hi;
      if (has_hl) hl[idx] = f2bf(nv - bf2f(hi));
    }
}

// ============================================================ t-MLP — unchanged
__global__ void __launch_bounds__(256) k_tmlp(
  const unsigned short* hb, const unsigned short* hl, int has_hl,
  const float* fc1f, const float* fc2f,
  const float* fc1b, const float* fc2b, unsigned short* Th, unsigned short* Tl)
{
  __shared__ float Xs[16][128];
  __shared__ float Hsm[16][128];
  int tid = threadIdx.x, wv = tid>>6, lane = tid&63;
  int nodeBase = blockIdx.x*16 + wv*4;
  for (int i=0;i<4;i++){
    size_t base = (size_t)(nodeBase+i)*128 + lane*2;
    float x0 = bf2f(hb[base]), x1 = bf2f(hb[base+1]);
    if (has_hl){ x0 += bf2f(hl[base]); x1 += bf2f(hl[base+1]); }
    Xs[wv*4+i][lane*2] = x0; Xs[wv*4+i][lane*2+1] = x1;
  }
  __syncthreads();
  float a0[4], a1[4];
  for (int i=0;i<4;i++){ a0[i] = fc1b[lane*2]; a1[i] = fc1b[lane*2+1]; }
  for (int k=0;k<128;k++){
    f32x2 w = *(const f32x2*)&fc1f[k*128 + lane*2];
    for (int i=0;i<4;i++){ float x = Xs[wv*4+i][k]; a0[i] += x*w[0]; a1[i] += x*w[1]; }
  }
  for (int i=0;i<4;i++){
    Hsm[wv*4+i][lane*2]   = fmaxf(a0[i], 0.f);
    Hsm[wv*4+i][lane*2+1] = fmaxf(a1[i], 0.f);
  }
  __syncthreads();
  for (int i=0;i<4;i++){ a0[i] = fc2b[lane*2]; a1[i] = fc2b[lane*2+1]; }
  for (int k=0;k<128;k++){
    f32x2 w = *(const f32x2*)&fc2f[k*128 + lane*2];
    for (int i=0;i<4;i++){ float x = Hsm[wv*4+i][k]; a0[i] += x*w[0]; a1[i] += x*w[1]; }
  }
  for (int i=0;i<4;i++){
    size_t idx = (size_t)(nodeBase+i)*128 + lane*2;
    float t0 = a0[i], t1 = a1[i];
    unsigned short h0 = f2bf(t0), h1 = f2bf(t1);
    Th[idx] = h0; Th[idx+1] = h1;
    Tl[idx]   = f2bf(t0 - bf2f(h0));
    Tl[idx+1] = f2bf(t1 - bf2f(h1));
  }
}

// ============================================================ per-pair — unchanged
__global__ void __launch_bounds__(256) k_pair(
  const unsigned short* Th, const unsigned short* Tl,
  const unsigned short* hb, const unsigned short* hl, int has_hl,
  void* outv, const int* flag)
{
  __shared__ float la[8448];
  __shared__ float red[4];
  const u16x8* th8 = (const u16x8*)Th;
  const u16x8* tl8 = (const u16x8*)Tl;
  int b = blockIdx.x;
  int even = ((b & 1) == 0);
  int qs = even ? 128 : 64;
  int cs = 192 - qs;
  int nr = even ? 128 : 65;
  int nc = even ? 65 : 128;
  int st = nc + 1;
  int q0 = 192*b, c0 = q0 + qs;
  int tid = threadIdx.x, wv = tid>>6, lane = tid&63, quad = lane>>4, l15 = lane&15;
  u16x8 zero8 = {0,0,0,0,0,0,0,0};

  f32x4 acc[2][8];
  for (int a=0;a<2;a++)
    for (int c=0;c<8;c++){ f32x4 z = {0.f,0.f,0.f,0.f}; acc[a][c]=z; }
  for (int pass=0; pass<3; ++pass){
    const u16x8* A  = (pass==2) ? tl8 : th8;
    const u16x8* Bm = (pass==1) ? tl8 : th8;
    for (int ks=0; ks<4; ++ks){
      u16x8 av[2], bv[8];
      for (int mt=0; mt<2; ++mt){
        int q = wv*32 + mt*16 + l15;
        av[mt] = (q < qs) ? A[(size_t)(q0+q)*16 + ks*4 + quad] : zero8;
      }
      for (int nt=0; nt<8; ++nt){
        int c = nt*16 + l15;
        bv[nt] = (c < cs) ? Bm[(size_t)(c0+c)*16 + ks*4 + quad] : zero8;
      }
      for (int mt=0; mt<2; ++mt)
        for (int nt=0; nt<8; ++nt)
          acc[mt][nt] = mfma16(av[mt], bv[nt], acc[mt][nt]);
    }
  }
  for (int mt=0; mt<2; ++mt)
    for (int nt=0; nt<8; ++nt)
      for (int r=0;r<4;r++){
        int q = wv*32 + mt*16 + quad*4 + r;
        int c = nt*16 + l15;
        if (q < nr && c < nc) la[q*st + c] = acc[mt][nt][r] * 10.0f;
      }
  __syncthreads();

  for (int it=0; it<20; ++it){
    if (tid < nr){
      float* row = &la[tid*st];
      float mx = -1e30f;
      for (int c=0;c<nc;c++) mx = fmaxf(mx, row[c]);
      float s = 0.f, last = 0.f;
      for (int c=0;c<nc;c++){ float e = __expf(row[c]-mx); s += e; last = e; }
      if (even) s += 63.f * last;
      float l = mx + __logf(s);
      for (int c=0;c<nc;c++) row[c] -= l;
    }
    __syncthreads();
    if (tid < nc){
      int c = tid;
      float mx = -1e30f;
      for (int r=0;r<nr;r++) mx = fmaxf(mx, la[r*st + c]);
      float s = 0.f, last = 0.f;
      for (int r=0;r<nr;r++){ float e = __expf(la[r*st + c]-mx); s += e; last = e; }
      if (!even) s += 63.f * last;
      float l = mx + __logf(s);
      for (int r=0;r<nr;r++) la[r*st + c] -= l;
    }
    __syncthreads();
  }
  for (int i = tid; i < 8448; i += 256) la[i] = __expf(la[i]);
  __syncthreads();

  int d = tid & 127, qg = tid >> 7;
  int nsweep = (nr + 15) >> 4;
  float partial = 0.f;
  for (int sweep=0; sweep<nsweep; ++sweep){
    int qb = sweep*16 + qg*8;
    float acc2[8];
    for (int j=0;j<8;j++) acc2[j] = 0.f;
    for (int c=0; c<cs; ++c){
      size_t si = (size_t)(c0+c)*128 + d;
      float s = bf2f(hb[si]);
      if (has_hl) s += bf2f(hl[si]);
      for (int j=0;j<8;j++){
        int r = qb + j;
        if (r < nr) acc2[j] += la[r*st + c] * s;
      }
    }
    for (int j=0;j<8;j++){
      int r = qb + j;
      if (r < nr){
        float w = (!even && r == 64) ? 64.f : 1.f;
        float sq = 0.f;
        if (r < qs){
          size_t si = (size_t)(q0+r)*128 + d;
          sq = bf2f(hb[si]);
          if (has_hl) sq += bf2f(hl[si]);
        }
        partial += w * fmaxf(sq - acc2[j], 0.f);
      }
    }
  }
  for (int off=32; off>0; off>>=1) partial += __shfl_down(partial, off, 64);
  if (lane == 0) red[wv] = partial;
  __syncthreads();
  if (tid == 0){
    float tot = red[0] + red[1] + red[2] + red[3];
    if (*flag) ((unsigned short*)outv)[b] = f2bf(-tot);
    else       ((float*)outv)[b] = -tot;
  }
}

// ============================================================ host
extern "C" void kernel_launch(void* const* d_in, const int* in_sizes, int n_in,
                              void* d_out, int out_size, void* d_ws, size_t ws_size,
                              hipStream_t stream)
{
  if (ws_size < WS_MINI){
    k_sent<<<2, 256, 0, stream>>>((float*)d_out);
    return;
  }
  int has_hl = 0, use_s8 = 0;
  size_t off_csr = 0;
  if (ws_size >= WS_FULL_G){ has_hl = 1; use_s8 = 1; off_csr = WS_FULL; }
  else if (ws_size >= WS_FULL){ has_hl = 1; use_s8 = 0; }
  else if (ws_size >= WS_MINI_G){ has_hl = 0; use_s8 = 1; off_csr = WS_MINI; }

  const int* from_idx = (const int*)d_in[22];
  const int* to_idx   = (const int*)d_in[23];

  char* wsb = (char*)d_ws;
  unsigned short* hb  = (unsigned short*)(wsb + OFF_HB);
  unsigned short* hl  = (unsigned short*)(wsb + OFF_HL);
  float* agg          = (float*)(wsb + OFF_AGG);
  unsigned short* Th  = (unsigned short*)(wsb + OFF_TH);
  unsigned short* Tl  = (unsigned short*)(wsb + OFF_TL);
  int* flag           = (int*)(wsb + OFF_W + WO_FLAG);

  const unsigned short* w1tm = (const unsigned short*)(wsb + OFF_W + WO_W1TM);
  const unsigned short* w1tr = (const unsigned short*)(wsb + OFF_W + WO_W1TR);
  const unsigned short* w2tm = (const unsigned short*)(wsb + OFF_W + WO_W2TM);
  const unsigned short* w2tr = (const unsigned short*)(wsb + OFF_W + WO_W2TR);
  const unsigned short* w1tu = (const unsigned short*)(wsb + OFF_W + WO_W1TU);
  const unsigned short* w2tu = (const unsigned short*)(wsb + OFF_W + WO_W2TU);
  const unsigned short* wnt  = (const unsigned short*)(wsb + OFF_W + WO_WNT);
  const unsigned short* wetp = (const unsigned short*)(wsb + OFF_W + WO_WETP);
  const float* fc1f  = (const float*)(wsb + OFF_W + WO_FC1F);
  const float* fc2f  = (const float*)(wsb + OFF_W + WO_FC2F);
  const float* bnf   = (const float*)(wsb + OFF_W + WO_BNF);
  const float* bef   = (const float*)(wsb + OFF_W + WO_BEF);
  const float* b1m   = (const float*)(wsb + OFF_W + WO_B1M);
  const float* b2m   = (const float*)(wsb + OFF_W + WO_B2M);
  const float* b1r   = (const float*)(wsb + OFF_W + WO_B1R);
  const float* b2r   = (const float*)(wsb + OFF_W + WO_B2R);
  const float* b1u   = (const float*)(wsb + OFF_W + WO_B1U);
  const float* b2u   = (const float*)(wsb + OFF_W + WO_B2U);
  const float* f1b   = (const float*)(wsb + OFF_W + WO_FC1B);
  const float* f2b   = (const float*)(wsb + OFF_W + WO_FC2B);

  int* offs0 = (int*)(wsb + off_csr);
  int* offs1 = offs0 + (NN + 1);
  int* cur0  = offs1 + (NN + 1);
  int* cur1  = cur0 + NN;
  int* ent0  = cur1 + NN;
  int* ent1  = ent0 + NE;
  int* csum  = ent1 + NE;

  k_dtype<<<1, 64, 0, stream>>>((const unsigned short*)d_in[0], flag);

  k_canary<<<2, 256, 0, stream>>>(d_out, flag);

  k_prep<<<1439, 256, 0, stream>>>(
    d_in[2],  d_in[3],  d_in[4],  d_in[5],
    d_in[6],  d_in[7],  d_in[8],  d_in[9],
    d_in[10], d_in[11], d_in[12], d_in[13],
    d_in[14], d_in[15], d_in[16], d_in[17],
    d_in[18], d_in[19], d_in[20], d_in[21],
    wsb);

  if (use_s8){
    k_csr_zero <<<NN/256, 256, 0, stream>>>(cur0, cur1);
    k_csr_count<<<NE/256, 256, 0, stream>>>(from_idx, to_idx, cur0, cur1);
    k_scan1    <<<2*SCAN_CHUNKS, 256, 0, stream>>>(cur0, cur1, csum);
    k_scan2    <<<1, 128, 0, stream>>>(csum, offs0, offs1);
    k_scan3    <<<2*SCAN_CHUNKS, 256, 0, stream>>>(cur0, cur1, csum, offs0, offs1);
    k_csr_fill <<<NE/256, 256, 0, stream>>>(from_idx, to_idx, cur0, cur1, ent0, ent1);
  }

  k_enc_node<<<NN/64, 256, 0, stream>>>(d_in[0], wnt, bnf, hb, hl, has_hl, flag);

  k_zero<<<3072, 256, 0, stream>>>(agg);   // round-0 only; later rounds fused into k_upd
  for (int r=0; r<5; ++r){
    if (use_s8){
      k_msg8<<<NE/64, 512, 0, stream>>>(hb, d_in[1],
          from_idx, to_idx, ent0, w1tm, w1tr, w2tm, w2tr, wetp, bef,
          b1m, b2m, b1r, b2r, agg, flag);
    } else {
      k_msg<<<NE/32, 256, 0, stream>>>(hb, d_in[1],
          from_idx, to_idx, w1tm, w1tr, w2tm, w2tr, wetp, bef,
          b1m, b2m, b1r, b2r, agg, flag);
    }
    k_upd<<<NN/64, 512, 0, stream>>>(agg, hb, w1tu, w2tu, b1u, b2u, hb, hl, has_hl);
  }

  k_tmlp<<<NN/16, 256, 0, stream>>>(hb, hl, has_hl, fc1f, fc2f, f1b, f2b, Th, Tl);
  k_pair<<<NB, 256, 0, stream>>>(Th, Tl, hb, hl, has_hl, d_out, flag);
}

// Round 9
// 5807.221 us; speedup vs baseline: 1.0339x; 1.0015x over previous
//
#include <hip/hip_runtime.h>

using bf16x8 = __attribute__((ext_vector_type(8))) __bf16;
using u16x8  = __attribute__((ext_vector_type(8))) unsigned short;
using f32x4  = __attribute__((ext_vector_type(4))) float;
using f32x2  = __attribute__((ext_vector_type(2))) float;

#define DEV static __device__ __forceinline__

constexpr int NN = 98304;     // total nodes  (512 pairs * 192)
constexpr int NE = 786432;    // total edges  (8 * NN)
constexpr int NB = 512;       // pairs

// ---------------- workspace layout (bytes) ----------------
constexpr size_t OFF_HB  = 0;                                  // hb : NN*128 bf16 (25.2MB)
constexpr size_t OFF_AGG = OFF_HB + (size_t)NN*128*2;          // agg: NN*128 f32  (50.3MB)
constexpr size_t OFF_TH  = OFF_AGG;                            // Th aliases agg[0:25.2MB]
constexpr size_t OFF_TL  = OFF_AGG + (size_t)NN*128*2;         // Tl aliases agg[25.2:50.3MB]
constexpr size_t OFF_W   = OFF_AGG + (size_t)NN*128*4;         // weight area

constexpr size_t WO_W1TM = 0;                                  // [256][320] bf16
constexpr size_t WO_W1TR = WO_W1TM + (size_t)81920*2;
constexpr size_t WO_W2TM = WO_W1TR + (size_t)81920*2;          // [128][256] bf16
constexpr size_t WO_W2TR = WO_W2TM + (size_t)32768*2;
constexpr size_t WO_W1TU = WO_W2TR + (size_t)32768*2;          // [256][256] bf16
constexpr size_t WO_W2TU = WO_W1TU + (size_t)65536*2;          // [128][256] bf16
constexpr size_t WO_WNT  = WO_W2TU + (size_t)32768*2;          // [128][32] bf16
constexpr size_t WO_WETP = WO_WNT  + (size_t)4096*2;           // [64][32] bf16 (k>=16 zero)
constexpr size_t WO_FC1F = WO_WETP + (size_t)2048*2;           // [128][128] f32
constexpr size_t WO_FC2F = WO_FC1F + (size_t)16384*4;
constexpr size_t WO_BNF  = WO_FC2F + (size_t)16384*4;          // biases f32
constexpr size_t WO_BEF  = WO_BNF + 128*4;
constexpr size_t WO_B1M  = WO_BEF + 64*4;
constexpr size_t WO_B2M  = WO_B1M + 256*4;
constexpr size_t WO_B1R  = WO_B2M + 128*4;
constexpr size_t WO_B2R  = WO_B1R + 256*4;
constexpr size_t WO_B1U  = WO_B2R + 128*4;
constexpr size_t WO_B2U  = WO_B1U + 256*4;
constexpr size_t WO_FC1B = WO_B2U + 128*4;
constexpr size_t WO_FC2B = WO_FC1B + 128*4;
constexpr size_t WO_FLAG = WO_FC2B + 128*4;                    // int dtype flag
constexpr size_t WO_END  = WO_FLAG + 16;

constexpr size_t OFF_HL  = OFF_W + WO_END;                     // hl : NN*128 bf16 (full only)
constexpr size_t WS_MINI = OFF_HL;                             // ~76.3 MB
constexpr size_t WS_FULL = OFF_HL + (size_t)NN*128*2;          // ~101.5 MB

// ---------------- CSR region (byte-identical to prior tiers) ----------------
constexpr int    SCAN_CHUNKS= NN/256;                          // 384
constexpr size_t CSR_INTS   = (size_t)2*(NN+1) + (size_t)2*NN + (size_t)2*NE + 768;
constexpr size_t CSR_BYTES  = CSR_INTS*4;                      // ~7.5 MB
constexpr size_t WS_FULL_G  = WS_FULL + CSR_BYTES;             // ~109.3 MB (confirmed avail)
constexpr size_t WS_MINI_G  = WS_MINI + CSR_BYTES;             // ~84.2 MB

// ---------------- G2 extension: materialized dir1 messages ----------------
constexpr size_t OFF_INV0 = WS_FULL_G;                         // inv0[NE] : e -> ent0 slot
constexpr size_t OFF_M1   = OFF_INV0 + (size_t)NE*4;           // m1[NE][128] bf16 (201MB)
constexpr size_t WS_G2    = OFF_M1 + (size_t)NE*128*2;         // ~313.8 MB

DEV unsigned short f2bf(float f){
  unsigned u = __float_as_uint(f);
  u += 0x7fffu + ((u >> 16) & 1u);          // RNE
  return (unsigned short)(u >> 16);
}
DEV float bf2f(unsigned short s){ return __uint_as_float(((unsigned)s) << 16); }

DEV unsigned short ldbf(const void* p, size_t i, int fl){
  return fl ? ((const unsigned short*)p)[i] : f2bf(((const float*)p)[i]);
}
DEV float ldf(const void* p, size_t i, int fl){
  return fl ? bf2f(((const unsigned short*)p)[i]) : ((const float*)p)[i];
}

DEV f32x4 mfma16(u16x8 a, u16x8 b, f32x4 c){
  bf16x8 A, B;
  __builtin_memcpy(&A, &a, 16);
  __builtin_memcpy(&B, &b, 16);
  return __builtin_amdgcn_mfma_f32_16x16x32_bf16(A, B, c, 0, 0, 0);
}

// ============================================================ dtype probe
__global__ void k_dtype(const unsigned short* nf_u16, int* flag){
  if (threadIdx.x != 0 || blockIdx.x != 0) return;
  int sane = 0;
  for (int i = 0; i < 64; ++i){
    unsigned short v = nf_u16[2*i];
    int e = (v >> 7) & 0xFF;
    if (e >= 0x70 && e <= 0x8E) sane++;
  }
  *flag = (sane >= 32) ? 1 : 0;
}

// ============================================================ ws-too-small sentinel
__global__ void k_sent(float* out){
  int i = blockIdx.x*256 + threadIdx.x;
  if (i < NB) out[i] = 10000.f;
}

// ============================================================ canary
__global__ void k_canary(void* out, const int* flag){
  int i = blockIdx.x*256 + threadIdx.x;
  if (i < NB){
    if (*flag) ((unsigned short*)out)[i] = (unsigned short)0x4580u;
    else       ((float*)out)[i] = 4096.f;
  }
}

// ============================================================ zero agg (round-0 only)
__global__ void k_zero(float* agg){
  f32x4* p = (f32x4*)agg;
  int gtid = blockIdx.x*256 + threadIdx.x;
  for (int i = gtid; i < NN*128/4; i += 786432){
    f32x4 z = {0.f, 0.f, 0.f, 0.f};
    p[i] = z;
  }
}

// ============================================================ prep: transpose/convert weights
__global__ void k_prep(
  const void* enc_node_w, const void* enc_node_b,
  const void* enc_edge_w, const void* enc_edge_b,
  const void* msg_w1, const void* msg_b1,
  const void* msg_w2, const void* msg_b2,
  const void* rmsg_w1, const void* rmsg_b1,
  const void* rmsg_w2, const void* rmsg_b2,
  const void* upd_w1, const void* upd_b1,
  const void* upd_w2, const void* upd_b2,
  const void* fc1_w, const void* fc1_b,
  const void* fc2_w, const void* fc2_b,
  char* wsb)
{
  int fl = *(const int*)(wsb + OFF_W + WO_FLAG);
  int i = blockIdx.x*256 + threadIdx.x;
  unsigned short* W1Tm = (unsigned short*)(wsb + OFF_W + WO_W1TM);
  unsigned short* W1Tr = (unsigned short*)(wsb + OFF_W + WO_W1TR);
  unsigned short* W2Tm = (unsigned short*)(wsb + OFF_W + WO_W2TM);
  unsigned short* W2Tr = (unsigned short*)(wsb + OFF_W + WO_W2TR);
  unsigned short* W1Tu = (unsigned short*)(wsb + OFF_W + WO_W1TU);
  unsigned short* W2Tu = (unsigned short*)(wsb + OFF_W + WO_W2TU);
  unsigned short* WnT  = (unsigned short*)(wsb + OFF_W + WO_WNT);
  unsigned short* WeTp = (unsigned short*)(wsb + OFF_W + WO_WETP);
  float* fc1f = (float*)(wsb + OFF_W + WO_FC1F);
  float* fc2f = (float*)(wsb + OFF_W + WO_FC2F);
  float* bnf  = (float*)(wsb + OFF_W + WO_BNF);
  float* bef  = (float*)(wsb + OFF_W + WO_BEF);
  float* b1m  = (float*)(wsb + OFF_W + WO_B1M);
  float* b2m  = (float*)(wsb + OFF_W + WO_B2M);
  float* b1r  = (float*)(wsb + OFF_W + WO_B1R);
  float* b2r  = (float*)(wsb + OFF_W + WO_B2R);
  float* b1u  = (float*)(wsb + OFF_W + WO_B1U);
  float* b2u  = (float*)(wsb + OFF_W + WO_B2U);
  float* f1b  = (float*)(wsb + OFF_W + WO_FC1B);
  float* f2b  = (float*)(wsb + OFF_W + WO_FC2B);

  if (i < 81920){ W1Tm[i] = ldbf(msg_w1,  (size_t)(i%320)*256 + (i/320), fl); return; } i -= 81920;
  if (i < 81920){ W1Tr[i] = ldbf(rmsg_w1, (size_t)(i%320)*256 + (i/320), fl); return; } i -= 81920;
  if (i < 32768){ W2Tm[i] = ldbf(msg_w2,  (size_t)(i%256)*128 + (i/256), fl); return; } i -= 32768;
  if (i < 32768){ W2Tr[i] = ldbf(rmsg_w2, (size_t)(i%256)*128 + (i/256), fl); return; } i -= 32768;
  if (i < 65536){ W1Tu[i] = ldbf(upd_w1,  (size_t)(i%256)*256 + (i/256), fl); return; } i -= 65536;
  if (i < 32768){ W2Tu[i] = ldbf(upd_w2,  (size_t)(i%256)*128 + (i/256), fl); return; } i -= 32768;
  if (i <  4096){ WnT[i]  = ldbf(enc_node_w, (size_t)(i%32)*128 + (i/32), fl); return; } i -= 4096;
  if (i <  2048){ int k = i%32, n = i/32;
                  WeTp[i] = (k<16) ? ldbf(enc_edge_w, (size_t)k*64 + n, fl) : (unsigned short)0; return; } i -= 2048;
  if (i < 16384){ fc1f[i] = ldf(fc1_w, i, fl); return; } i -= 16384;
  if (i < 16384){ fc2f[i] = ldf(fc2_w, i, fl); return; } i -= 16384;
  if (i <   128){ bnf[i] = ldf(enc_node_b, i, fl); return; } i -= 128;
  if (i <    64){ bef[i] = ldf(enc_edge_b, i, fl); return; } i -= 64;
  if (i <   256){ b1m[i] = ldf(msg_b1, i, fl); return; } i -= 256;
  if (i <   128){ b2m[i] = ldf(msg_b2, i, fl); return; } i -= 128;
  if (i <   256){ b1r[i] = ldf(rmsg_b1, i, fl); return; } i -= 256;
  if (i <   128){ b2r[i] = ldf(rmsg_b2, i, fl); return; } i -= 128;
  if (i <   256){ b1u[i] = ldf(upd_b1, i, fl); return; } i -= 256;
  if (i <   128){ b2u[i] = ldf(upd_b2, i, fl); return; } i -= 128;
  if (i <   128){ f1b[i] = ldf(fc1_b, i, fl); return; } i -= 128;
  if (i <   128){ f2b[i] = ldf(fc2_b, i, fl); return; }
}

// ============================================================ CSR build (one-time per call)
__global__ void k_csr_zero(int* cur0, int* cur1){
  int i = blockIdx.x*256 + threadIdx.x;
  if (i < NN){ cur0[i] = 0; cur1[i] = 0; }
}
__global__ void k_csr_count(const int* from_idx, const int* to_idx, int* cur0, int* cur1){
  int e = blockIdx.x*256 + threadIdx.x;
  if (e < NE){
    atomicAdd(&cur0[to_idx[e]], 1);
    atomicAdd(&cur1[from_idx[e]], 1);
  }
}
__global__ void k_scan1(const int* cur0, const int* cur1, int* csum){
  __shared__ int red[256];
  int b = blockIdx.x, tid = threadIdx.x;
  const int* c = (b >= SCAN_CHUNKS) ? cur1 : cur0;
  int cb = (b >= SCAN_CHUNKS) ? (b - SCAN_CHUNKS) : b;
  red[tid] = c[cb*256 + tid];
  __syncthreads();
  for (int off = 128; off > 0; off >>= 1){
    if (tid < off) red[tid] += red[tid + off];
    __syncthreads();
  }
  if (tid == 0) csum[b] = red[0];
}
__global__ void k_scan2(int* csum, int* offs0, int* offs1){
  int wv = threadIdx.x >> 6, lane = threadIdx.x & 63;
  if (wv >= 2) return;
  int basei = wv * SCAN_CHUNKS;
  int carry = 0;
  for (int j = 0; j < SCAN_CHUNKS/64; ++j){
    int x = csum[basei + j*64 + lane];
    int s = x;
    for (int off = 1; off < 64; off <<= 1){
      int t = __shfl_up(s, off, 64);
      if (lane >= off) s += t;
    }
    csum[basei + j*64 + lane] = s - x + carry;   // exclusive
    carry += __shfl(s, 63, 64);
  }
  if (lane == 0){
    if (wv == 0) offs0[NN] = carry; else offs1[NN] = carry;
  }
}
__global__ void k_scan3(int* cur0, int* cur1, const int* csum, int* offs0, int* offs1){
  __shared__ int s[256];
  int b = blockIdx.x, tid = threadIdx.x;
  int dir = (b >= SCAN_CHUNKS) ? 1 : 0;
  int cb  = dir ? (b - SCAN_CHUNKS) : b;
  int* c    = dir ? cur1 : cur0;
  int* offs = dir ? offs1 : offs0;
  int v = c[cb*256 + tid];
  s[tid] = v;
  __syncthreads();
  for (int off = 1; off < 256; off <<= 1){
    int t = (tid >= off) ? s[tid - off] : 0;
    __syncthreads();
    s[tid] += t;
    __syncthreads();
  }
  int excl = s[tid] - v + csum[b];
  offs[cb*256 + tid] = excl;
  c[cb*256 + tid] = excl;          // cursor = start offset
}
__global__ void k_csr_fill(const int* from_idx, const int* to_idx,
                           int* cur0, int* cur1, int* ent0, int* ent1, int* inv0){
  int e = blockIdx.x*256 + threadIdx.x;
  if (e < NE){
    int p0 = atomicAdd(&cur0[to_idx[e]], 1);   ent0[p0] = e;
    if (inv0) inv0[e] = p0;
    int p1 = atomicAdd(&cur1[from_idx[e]], 1); ent1[p1] = e;
  }
}

// ============================================================ node encoder
__global__ void __launch_bounds__(256) k_enc_node(
  const void* nf, const unsigned short* wnt, const float* bnf,
  unsigned short* hb, unsigned short* hl, int has_hl, const int* flag)
{
  int fl = *flag;
  const u16x8* wnt8 = (const u16x8*)wnt;
  int tid = threadIdx.x, wv = tid>>6, lane = tid&63, quad = lane>>4, l15 = lane&15;
  int n0 = blockIdx.x*64;
  f32x4 acc[4][2];
  for (int a=0;a<4;a++){ f32x4 z = {0.f,0.f,0.f,0.f}; acc[a][0]=z; acc[a][1]=z; }
  u16x8 av[4], bv[2];
  if (fl){
    const u16x8* nf8 = (const u16x8*)nf;
    for (int mt=0; mt<4; ++mt) av[mt] = nf8[(size_t)(n0 + mt*16 + l15)*4 + quad];
  } else {
    const float* nff = (const float*)nf;
    for (int mt=0; mt<4; ++mt){
      const float* rp = nff + (size_t)(n0 + mt*16 + l15)*32 + quad*8;
      u16x8 v;
      for (int j=0;j<8;j++) v[j] = f2bf(rp[j]);
      av[mt] = v;
    }
  }
  for (int nt=0; nt<2; ++nt) bv[nt] = wnt8[(size_t)(wv*32 + nt*16 + l15)*4 + quad];
  for (int mt=0; mt<4; ++mt)
    for (int nt=0; nt<2; ++nt)
      acc[mt][nt] = mfma16(av[mt], bv[nt], acc[mt][nt]);
  for (int mt=0; mt<4; ++mt)
    for (int nt=0; nt<2; ++nt){
      int n = wv*32 + nt*16 + l15;
      float bias = bnf[n];
      for (int r=0;r<4;r++){
        int m = mt*16 + quad*4 + r;
        float v = acc[mt][nt][r] + bias;
        size_t idx = (size_t)(n0+m)*128 + n;
        unsigned short hi = f2bf(v);
        hb[idx] = hi;
        if (has_hl) hl[idx] = f2bf(v - bf2f(hi));
      }
    }
}

// ============================================================ message kernel (ATOMIC FALLBACK)
__global__ void __launch_bounds__(256) k_msg(
  const unsigned short* hbg, const void* efg,
  const int* from_idx, const int* to_idx,
  const unsigned short* w1tm, const unsigned short* w1tr,
  const unsigned short* w2tm, const unsigned short* w2tr,
  const unsigned short* wetp, const float* bef,
  const float* b1m, const float* b2m, const float* b1r, const float* b2r,
  float* agg, const int* flag)
{
  __shared__ __align__(16) unsigned short XsB[40*32*8];   // 20480 B
  __shared__ __align__(16) unsigned short HsB[32*32*8];   // 16384 B
  __shared__ int fromS[32], toS[32];
  int fl = *flag;
  u16x8* Xs = (u16x8*)XsB;
  u16x8* Hs = (u16x8*)HsB;
  const u16x8* hb8   = (const u16x8*)hbg;
  const u16x8* wetp8 = (const u16x8*)wetp;
  const u16x8* w1tm8 = (const u16x8*)w1tm;
  const u16x8* w1tr8 = (const u16x8*)w1tr;
  const u16x8* w2tm8 = (const u16x8*)w2tm;
  const u16x8* w2tr8 = (const u16x8*)w2tr;

  int tid = threadIdx.x;
  int e0 = blockIdx.x*32;
  if (tid < 32) fromS[tid] = from_idx[e0 + tid];
  else if (tid < 64) toS[tid-32] = to_idx[e0 + tid - 32];
  __syncthreads();
  int m = tid & 31, g = tid >> 5;
  int wv = tid>>6, lane = tid&63, quad = lane>>4, l15 = lane&15;
  u16x8 zero8 = {0,0,0,0,0,0,0,0};

  for (int j=0; j<4; ++j){
    int kb = g + 8*j;
    u16x8 v = (kb < 16) ? hb8[(size_t)fromS[m]*16 + kb]
                        : hb8[(size_t)toS[m]*16 + (kb-16)];
    Xs[kb*32 + m] = v;
  }
  {
    f32x4 accE[2];
    for (int a=0;a<2;a++){ f32x4 z = {0.f,0.f,0.f,0.f}; accE[a]=z; }
    u16x8 bvE = wetp8[(size_t)(wv*16 + l15)*4 + quad];
    for (int mt=0; mt<2; ++mt){
      u16x8 avE = zero8;
      if (quad < 2){
        if (fl){
          avE = ((const u16x8*)efg)[(size_t)(e0 + mt*16 + l15)*2 + quad];
        } else {
          const float* ep = (const float*)efg + (size_t)(e0 + mt*16 + l15)*16 + quad*8;
          u16x8 v;
          for (int j=0;j<8;j++) v[j] = f2bf(ep[j]);
          avE = v;
        }
      }
      accE[mt] = mfma16(avE, bvE, accE[mt]);
    }
    int n = wv*16 + l15;
    float bias = bef[n];
    for (int mt=0; mt<2; ++mt)
      for (int r=0;r<4;r++){
        int me = mt*16 + quad*4 + r;
        XsB[((32 + (n>>3))*32 + me)*8 + (n&7)] = f2bf(accE[mt][r] + bias);
      }
  }
  __syncthreads();

  for (int dir=0; dir<2; ++dir){
    const u16x8* W1T = dir ? w1tr8 : w1tm8;
    const u16x8* W2T = dir ? w2tr8 : w2tm8;
    const float* B1  = dir ? b1r : b1m;
    const float* B2  = dir ? b2r : b2m;
    f32x4 acc1[2][4];
    for (int a=0;a<2;a++)
      for (int b=0;b<4;b++){ f32x4 z = {0.f,0.f,0.f,0.f}; acc1[a][b]=z; }
    for (int ks=0; ks<10; ++ks){
      u16x8 bv[4], av[2];
      for (int nt=0; nt<4; ++nt)
        bv[nt] = W1T[(size_t)(wv*64 + nt*16 + l15)*40 + ks*4 + quad];
      int kb = ks*4 + quad;
      int kbm = dir ? (kb < 32 ? (kb ^ 16) : kb) : kb;
      for (int mt=0; mt<2; ++mt)
        av[mt] = Xs[kbm*32 + mt*16 + l15];
      for (int mt=0; mt<2; ++mt)
        for (int nt=0; nt<4; ++nt)
          acc1[mt][nt] = mfma16(av[mt], bv[nt], acc1[mt][nt]);
    }
    __syncthreads();
    for (int mt=0; mt<2; ++mt)
      for (int nt=0; nt<4; ++nt){
        int n = wv*64 + nt*16 + l15;
        float bias = B1[n];
        for (int r=0;r<4;r++){
          int mm = mt*16 + quad*4 + r;
          float v = fmaxf(acc1[mt][nt][r] + bias, 0.f);
          HsB[((n>>3)*32 + mm)*8 + (n&7)] = f2bf(v);
        }
      }
    __syncthreads();
    f32x4 acc2[2][2];
    for (int a=0;a<2;a++)
      for (int b=0;b<2;b++){ f32x4 z = {0.f,0.f,0.f,0.f}; acc2[a][b]=z; }
    for (int ks=0; ks<8; ++ks){
      u16x8 bv[2], av[2];
      for (int nt=0; nt<2; ++nt)
        bv[nt] = W2T[(size_t)(wv*32 + nt*16 + l15)*32 + ks*4 + quad];
      for (int mt=0; mt<2; ++mt)
        av[mt] = Hs[(ks*4 + quad)*32 + mt*16 + l15];
      for (int mt=0; mt<2; ++mt)
        for (int nt=0; nt<2; ++nt)
          acc2[mt][nt] = mfma16(av[mt], bv[nt], acc2[mt][nt]);
    }
    for (int mt=0; mt<2; ++mt)
      for (int nt=0; nt<2; ++nt){
        int n = wv*32 + nt*16 + l15;
        float bias = B2[n];
        for (int r=0;r<4;r++){
          int mm = mt*16 + quad*4 + r;
          int row = dir ? fromS[mm] : toS[mm];
          atomicAdd(agg + (size_t)row*128 + n, acc2[mt][nt][r] + bias);
        }
      }
  }
}

// ============================================================ message kernel v8 (G tier): 64 edges/block
__global__ void __launch_bounds__(512, 4) k_msg8(
  const unsigned short* hbg, const void* efg,
  const int* from_idx, const int* to_idx, const int* ent,
  const unsigned short* w1tm, const unsigned short* w1tr,
  const unsigned short* w2tm, const unsigned short* w2tr,
  const unsigned short* wetp, const float* bef,
  const float* b1m, const float* b2m, const float* b1r, const float* b2r,
  float* agg, const int* flag)
{
  __shared__ __align__(16) unsigned short XsB[40*64*8];   // 40960 B
  __shared__ __align__(16) unsigned short HsB[32*64*8];   // 32768 B ; P (64x128 f32) aliases
  __shared__ int eS[64], fromS[64], toS[64];
  __shared__ int runBeg[65];
  __shared__ int nRunsS;
  int fl = *flag;
  u16x8* Xs = (u16x8*)XsB;
  u16x8* Hs = (u16x8*)HsB;
  const u16x8* hb8   = (const u16x8*)hbg;
  const u16x8* wetp8 = (const u16x8*)wetp;
  const u16x8* w1tm8 = (const u16x8*)w1tm;
  const u16x8* w1tr8 = (const u16x8*)w1tr;
  const u16x8* w2tm8 = (const u16x8*)w2tm;
  const u16x8* w2tr8 = (const u16x8*)w2tr;

  int tid = threadIdx.x;
  int cpx = (int)gridDim.x >> 3;
  int bb = ((int)blockIdx.x & 7) * cpx + ((int)blockIdx.x >> 3);
  int e0 = bb * 64;
  if (tid < 64){
    int e = ent[e0 + tid];
    eS[tid] = e;
    fromS[tid] = from_idx[e];
    toS[tid]   = to_idx[e];
  }
  __syncthreads();
  int w = tid>>6, lane = tid&63, quad = lane>>4, l15 = lane&15;
  u16x8 zero8 = {0,0,0,0,0,0,0,0};

  if (tid == 0){
    int nr = 0;
    for (int mm=0; mm<64; ++mm)
      if (mm==0 || toS[mm]!=toS[mm-1]) runBeg[nr++] = mm;
    runBeg[nr] = 64; nRunsS = nr;
  }
  {
    int edge = tid & 63, cg = tid >> 6;
    for (int j=0; j<4; ++j){
      int kb = cg + 8*j;
      u16x8 v = (kb < 16) ? hb8[(size_t)fromS[edge]*16 + kb]
                          : hb8[(size_t)toS[edge]*16 + (kb-16)];
      Xs[kb*64 + edge] = v;
    }
  }
  {
    int wm = w >> 2, wn = w & 3;
    f32x4 accE[2];
    for (int a=0;a<2;a++){ f32x4 z = {0.f,0.f,0.f,0.f}; accE[a]=z; }
    u16x8 bvE = wetp8[(size_t)(wn*16 + l15)*4 + quad];
    for (int mt=0; mt<2; ++mt){
      u16x8 avE = zero8;
      if (quad < 2){
        int e = eS[wm*32 + mt*16 + l15];
        if (fl){
          avE = ((const u16x8*)efg)[(size_t)e*2 + quad];
        } else {
          const float* ep = (const float*)efg + (size_t)e*16 + quad*8;
          u16x8 v;
          for (int j=0;j<8;j++) v[j] = f2bf(ep[j]);
          avE = v;
        }
      }
      accE[mt] = mfma16(avE, bvE, accE[mt]);
    }
    int n = wn*16 + l15;
    float bias = bef[n];
    for (int mt=0; mt<2; ++mt)
      for (int r=0;r<4;r++){
        int me = wm*32 + mt*16 + quad*4 + r;
        XsB[((32 + (n>>3))*64 + me)*8 + (n&7)] = f2bf(accE[mt][r] + bias);
      }
  }
  __syncthreads();

  for (int dir=0; dir<2; ++dir){
    const u16x8* W1T = dir ? w1tr8 : w1tm8;
    const u16x8* W2T = dir ? w2tr8 : w2tm8;
    const float* B1  = dir ? b1r : b1m;
    f32x4 acc1[4][2];
    for (int a=0;a<4;a++)
      for (int b=0;b<2;b++){ f32x4 z = {0.f,0.f,0.f,0.f}; acc1[a][b]=z; }
    for (int ks=0; ks<10; ++ks){
      u16x8 bv[2], av[4];
      for (int nt=0; nt<2; ++nt)
        bv[nt] = W1T[(size_t)(w*32 + nt*16 + l15)*40 + ks*4 + quad];
      int kb = ks*4 + quad;
      int kbm = dir ? (kb < 32 ? (kb ^ 16) : kb) : kb;
      for (int mt=0; mt<4; ++mt)
        av[mt] = Xs[kbm*64 + mt*16 + l15];
      for (int mt=0; mt<4; ++mt)
        for (int nt=0; nt<2; ++nt)
          acc1[mt][nt] = mfma16(av[mt], bv[nt], acc1[mt][nt]);
    }
    if (dir == 1) __syncthreads();
    for (int mt=0; mt<4; ++mt)
      for (int nt=0; nt<2; ++nt){
        int n = w*32 + nt*16 + l15;
        float bias = B1[n];
        for (int r=0;r<4;r++){
          int mm = mt*16 + quad*4 + r;
          float v = fmaxf(acc1[mt][nt][r] + bias, 0.f);
          HsB[((n>>3)*64 + mm)*8 + (n&7)] = f2bf(v);
        }
      }
    __syncthreads();
    f32x4 acc2[4];
    for (int a=0;a<4;a++){ f32x4 z = {0.f,0.f,0.f,0.f}; acc2[a]=z; }
    int n2 = w*16 + l15;
    for (int ks=0; ks<8; ++ks){
      u16x8 bv1 = W2T[(size_t)n2*32 + ks*4 + quad];
      u16x8 av[4];
      for (int mt=0; mt<4; ++mt)
        av[mt] = Hs[(ks*4 + quad)*64 + mt*16 + l15];
      for (int mt=0; mt<4; ++mt)
        acc2[mt] = mfma16(av[mt], bv1, acc2[mt]);
    }
    if (dir == 0){
      __syncthreads();
      float* P = (float*)HsB;
      float bias = b2m[n2];
      for (int mt=0; mt<4; ++mt)
        for (int r=0;r<4;r++){
          int mm = mt*16 + quad*4 + r;
          P[mm*128 + n2] = acc2[mt][r] + bias;
        }
      __syncthreads();
      int col = tid & 127, grp = tid >> 7;
      int nr = nRunsS;
      for (int k = grp; k < nr; k += 4){
        int r0 = runBeg[k], r1 = runBeg[k+1];
        float s = 0.f;
        for (int mm = r0; mm < r1; ++mm) s += P[mm*128 + col];
        atomicAdd(agg + (size_t)toS[r0]*128 + col, s);
      }
    } else {
      float bias = b2r[n2];
      for (int mt=0; mt<4; ++mt)
        for (int r=0;r<4;r++){
          int mm = mt*16 + quad*4 + r;
          atomicAdd(agg + (size_t)fromS[mm]*128 + n2, acc2[mt][r] + bias);
        }
    }
  }
}

// ============================================================ message kernel v10 (G2 tier): dir1 atomic-free
// Same as k_msg8 but dir1 messages are materialized to m1[slot] (slot = ent0
// position = e0+mm, block-contiguous coalesced bf16 rows). Zero dir1 atomics.
__global__ void __launch_bounds__(512, 4) k_msg10(
  const unsigned short* hbg, const void* efg,
  const int* from_idx, const int* to_idx, const int* ent,
  const unsigned short* w1tm, const unsigned short* w1tr,
  const unsigned short* w2tm, const unsigned short* w2tr,
  const unsigned short* wetp, const float* bef,
  const float* b1m, const float* b2m, const float* b1r, const float* b2r,
  float* agg, unsigned short* m1, const int* flag)
{
  __shared__ __align__(16) unsigned short XsB[40*64*8];   // 40960 B
  __shared__ __align__(16) unsigned short HsB[32*64*8];   // 32768 B ; P (64x128 f32) aliases
  __shared__ int eS[64], fromS[64], toS[64];
  __shared__ int runBeg[65];
  __shared__ int nRunsS;
  int fl = *flag;
  u16x8* Xs = (u16x8*)XsB;
  u16x8* Hs = (u16x8*)HsB;
  const u16x8* hb8   = (const u16x8*)hbg;
  const u16x8* wetp8 = (const u16x8*)wetp;
  const u16x8* w1tm8 = (const u16x8*)w1tm;
  const u16x8* w1tr8 = (const u16x8*)w1tr;
  const u16x8* w2tm8 = (const u16x8*)w2tm;
  const u16x8* w2tr8 = (const u16x8*)w2tr;

  int tid = threadIdx.x;
  int cpx = (int)gridDim.x >> 3;
  int bb = ((int)blockIdx.x & 7) * cpx + ((int)blockIdx.x >> 3);
  int e0 = bb * 64;
  if (tid < 64){
    int e = ent[e0 + tid];
    eS[tid] = e;
    fromS[tid] = from_idx[e];
    toS[tid]   = to_idx[e];
  }
  __syncthreads();
  int w = tid>>6, lane = tid&63, quad = lane>>4, l15 = lane&15;
  u16x8 zero8 = {0,0,0,0,0,0,0,0};

  if (tid == 0){
    int nr = 0;
    for (int mm=0; mm<64; ++mm)
      if (mm==0 || toS[mm]!=toS[mm-1]) runBeg[nr++] = mm;
    runBeg[nr] = 64; nRunsS = nr;
  }
  {
    int edge = tid & 63, cg = tid >> 6;
    for (int j=0; j<4; ++j){
      int kb = cg + 8*j;
      u16x8 v = (kb < 16) ? hb8[(size_t)fromS[edge]*16 + kb]
                          : hb8[(size_t)toS[edge]*16 + (kb-16)];
      Xs[kb*64 + edge] = v;
    }
  }
  {
    int wm = w >> 2, wn = w & 3;
    f32x4 accE[2];
    for (int a=0;a<2;a++){ f32x4 z = {0.f,0.f,0.f,0.f}; accE[a]=z; }
    u16x8 bvE = wetp8[(size_t)(wn*16 + l15)*4 + quad];
    for (int mt=0; mt<2; ++mt){
      u16x8 avE = zero8;
      if (quad < 2){
        int e = eS[wm*32 + mt*16 + l15];
        if (fl){
          avE = ((const u16x8*)efg)[(size_t)e*2 + quad];
        } else {
          const float* ep = (const float*)efg + (size_t)e*16 + quad*8;
          u16x8 v;
          for (int j=0;j<8;j++) v[j] = f2bf(ep[j]);
          avE = v;
        }
      }
      accE[mt] = mfma16(avE, bvE, accE[mt]);
    }
    int n = wn*16 + l15;
    float bias = bef[n];
    for (int mt=0; mt<2; ++mt)
      for (int r=0;r<4;r++){
        int me = wm*32 + mt*16 + quad*4 + r;
        XsB[((32 + (n>>3))*64 + me)*8 + (n&7)] = f2bf(accE[mt][r] + bias);
      }
  }
  __syncthreads();

  for (int dir=0; dir<2; ++dir){
    const u16x8* W1T = dir ? w1tr8 : w1tm8;
    const u16x8* W2T = dir ? w2tr8 : w2tm8;
    const float* B1  = dir ? b1r : b1m;
    f32x4 acc1[4][2];
    for (int a=0;a<4;a++)
      for (int b=0;b<2;b++){ f32x4 z = {0.f,0.f,0.f,0.f}; acc1[a][b]=z; }
    for (int ks=0; ks<10; ++ks){
      u16x8 bv[2], av[4];
      for (int nt=0; nt<2; ++nt)
        bv[nt] = W1T[(size_t)(w*32 + nt*16 + l15)*40 + ks*4 + quad];
      int kb = ks*4 + quad;
      int kbm = dir ? (kb < 32 ? (kb ^ 16) : kb) : kb;
      for (int mt=0; mt<4; ++mt)
        av[mt] = Xs[kbm*64 + mt*16 + l15];
      for (int mt=0; mt<4; ++mt)
        for (int nt=0; nt<2; ++nt)
          acc1[mt][nt] = mfma16(av[mt], bv[nt], acc1[mt][nt]);
    }
    if (dir == 1) __syncthreads();   // dir0 P-merge reads done before Hs overwrite
    for (int mt=0; mt<4; ++mt)
      for (int nt=0; nt<2; ++nt){
        int n = w*32 + nt*16 + l15;
        float bias = B1[n];
        for (int r=0;r<4;r++){
          int mm = mt*16 + quad*4 + r;
          float v = fmaxf(acc1[mt][nt][r] + bias, 0.f);
          HsB[((n>>3)*64 + mm)*8 + (n&7)] = f2bf(v);
        }
      }
    __syncthreads();                 // Hs ready
    f32x4 acc2[4];
    for (int a=0;a<4;a++){ f32x4 z = {0.f,0.f,0.f,0.f}; acc2[a]=z; }
    int n2 = w*16 + l15;
    for (int ks=0; ks<8; ++ks){
      u16x8 bv1 = W2T[(size_t)n2*32 + ks*4 + quad];
      u16x8 av[4];
      for (int mt=0; mt<4; ++mt)
        av[mt] = Hs[(ks*4 + quad)*64 + mt*16 + l15];
      for (int mt=0; mt<4; ++mt)
        acc2[mt] = mfma16(av[mt], bv1, acc2[mt]);
    }
    __syncthreads();                 // Hs reads done -> P may overwrite
    float* P = (float*)HsB;          // 64x128 f32 = 32768B exactly
    {
      float bias = dir ? b2r[n2] : b2m[n2];
      for (int mt=0; mt<4; ++mt)
        for (int r=0;r<4;r++){
          int mm = mt*16 + quad*4 + r;
          P[mm*128 + n2] = acc2[mt][r] + bias;
        }
    }
    __syncthreads();                 // P complete
    if (dir == 0){
      // merge runs + one atomic per (run,col)
      int col = tid & 127, grp = tid >> 7;
      int nr = nRunsS;
      for (int k = grp; k < nr; k += 4){
        int r0 = runBeg[k], r1 = runBeg[k+1];
        float s = 0.f;
        for (int mm = r0; mm < r1; ++mm) s += P[mm*128 + col];
        atomicAdd(agg + (size_t)toS[r0]*128 + col, s);
      }
    } else {
      // dir1: coalesced bf16 dump to m1 rows e0..e0+63 (zero atomics)
      for (int i = tid; i < 64*128; i += 512)
        m1[(size_t)(e0 + (i >> 7))*128 + (i & 127)] = f2bf(P[i]);
    }
  }
}

// ============================================================ node update (G tier): fused zero + 64 nodes
__global__ void __launch_bounds__(512, 4) k_upd(
  float* agg, const unsigned short* hbg,
  const unsigned short* w1tu, const unsigned short* w2tu,
  const float* b1u, const float* b2u,
  unsigned short* hb, unsigned short* hl, int has_hl)
{
  __shared__ __align__(16) unsigned short XsB[32*64*8];   // 32768 B
  __shared__ __align__(16) unsigned short HsB[32*64*8];   // 32768 B
  u16x8* Xs = (u16x8*)XsB;
  u16x8* Hs = (u16x8*)HsB;
  const u16x8* hb8   = (const u16x8*)hbg;
  const u16x8* w1tu8 = (const u16x8*)w1tu;
  const u16x8* w2tu8 = (const u16x8*)w2tu;
  int tid = threadIdx.x;
  int n0 = blockIdx.x*64;
  {
    int node = tid & 63, cg = tid >> 6;
    for (int j=0; j<4; ++j){
      int kb = cg + 8*j;
      u16x8 v;
      if (kb < 16){
        const float* ap = agg + (size_t)(n0+node)*128 + kb*8;
        for (int t=0;t<8;t++) v[t] = f2bf(ap[t]);
      } else {
        v = hb8[(size_t)(n0+node)*16 + (kb-16)];
      }
      Xs[kb*64 + node] = v;
    }
  }
  __syncthreads();
  {
    f32x4* ap4 = (f32x4*)(agg + (size_t)n0*128);
    f32x4 z = {0.f,0.f,0.f,0.f};
    for (int i = tid; i < 64*128/4; i += 512) ap4[i] = z;
  }
  int w = tid>>6, lane = tid&63, quad = lane>>4, l15 = lane&15;
  f32x4 acc1[4][2];
  for (int a=0;a<4;a++)
    for (int b=0;b<2;b++){ f32x4 z = {0.f,0.f,0.f,0.f}; acc1[a][b]=z; }
  for (int ks=0; ks<8; ++ks){
    u16x8 bv[2], av[4];
    for (int nt=0; nt<2; ++nt)
      bv[nt] = w1tu8[(size_t)(w*32 + nt*16 + l15)*32 + ks*4 + quad];
    for (int mt=0; mt<4; ++mt)
      av[mt] = Xs[(ks*4 + quad)*64 + mt*16 + l15];
    for (int mt=0; mt<4; ++mt)
      for (int nt=0; nt<2; ++nt)
        acc1[mt][nt] = mfma16(av[mt], bv[nt], acc1[mt][nt]);
  }
  __syncthreads();
  for (int mt=0; mt<4; ++mt)
    for (int nt=0; nt<2; ++nt){
      int n = w*32 + nt*16 + l15;
      float bias = b1u[n];
      for (int r=0;r<4;r++){
        int mm = mt*16 + quad*4 + r;
        float v = fmaxf(acc1[mt][nt][r] + bias, 0.f);
        HsB[((n>>3)*64 + mm)*8 + (n&7)] = f2bf(v);
      }
    }
  __syncthreads();
  f32x4 acc2[4];
  for (int a=0;a<4;a++){ f32x4 z = {0.f,0.f,0.f,0.f}; acc2[a]=z; }
  int n2 = w*16 + l15;
  for (int ks=0; ks<8; ++ks){
    u16x8 bv2 = w2tu8[(size_t)n2*32 + ks*4 + quad];
    u16x8 av[4];
    for (int mt=0; mt<4; ++mt)
      av[mt] = Hs[(ks*4 + quad)*64 + mt*16 + l15];
    for (int mt=0; mt<4; ++mt)
      acc2[mt] = mfma16(av[mt], bv2, acc2[mt]);
  }
  float bias = b2u[n2];
  for (int mt=0; mt<4; ++mt)
    for (int r=0;r<4;r++){
      int mm = mt*16 + quad*4 + r;
      size_t idx = (size_t)(n0+mm)*128 + n2;
      float base = bf2f(hb[idx]);
      if (has_hl) base += bf2f(hl[idx]);
      float nv = base + acc2[mt][r] + bias;
      unsigned short hi = f2bf(nv);
      hb[idx] = hi;
      if (has_hl) hl[idx] = f2bf(nv - bf2f(hi));
    }
}

// ============================================================ node update v2 (G2 tier): + dir1 gather from m1
// agg holds dir0 sums only; each thread-octet (node, 16-col chunk) gathers the
// node's dir1 message rows (ent1 contiguous, inv0 -> m1 slot) and sums in f32.
__global__ void __launch_bounds__(512, 4) k_upd2(
  float* agg, const unsigned short* m1, const int* ent1, const int* inv0,
  const int* offs1, const unsigned short* hbg,
  const unsigned short* w1tu, const unsigned short* w2tu,
  const float* b1u, const float* b2u,
  unsigned short* hb, unsigned short* hl, int has_hl)
{
  __shared__ __align__(16) unsigned short XsB[32*64*8];   // 32768 B
  __shared__ __align__(16) unsigned short HsB[32*64*8];   // 32768 B
  u16x8* Xs = (u16x8*)XsB;
  u16x8* Hs = (u16x8*)HsB;
  const u16x8* hb8   = (const u16x8*)hbg;
  const u16x8* m18   = (const u16x8*)m1;
  const u16x8* w1tu8 = (const u16x8*)w1tu;
  const u16x8* w2tu8 = (const u16x8*)w2tu;
  int tid = threadIdx.x;
  int n0 = blockIdx.x*64;
  // ---- agg(f32, dir0) + gathered dir1 rows -> Xs rows 0..15 (bf16)
  {
    int node = tid >> 3, chunk = tid & 7;   // 16 cols per thread
    float a[16];
    const f32x4* ap = (const f32x4*)(agg + (size_t)(n0+node)*128 + chunk*16);
    for (int q=0;q<4;q++){ f32x4 v = ap[q]; a[q*4]=v[0]; a[q*4+1]=v[1]; a[q*4+2]=v[2]; a[q*4+3]=v[3]; }
    int jb = offs1[n0+node], je = offs1[n0+node+1];
    for (int j = jb; j < je; ++j){
      int s = inv0[ent1[j]];
      u16x8 v0 = m18[(size_t)s*16 + chunk*2];
      u16x8 v1 = m18[(size_t)s*16 + chunk*2 + 1];
      for (int t=0;t<8;t++){ a[t] += bf2f(v0[t]); a[8+t] += bf2f(v1[t]); }
    }
    u16x8 o0, o1;
    for (int t=0;t<8;t++){ o0[t] = f2bf(a[t]); o1[t] = f2bf(a[8+t]); }
    Xs[(chunk*2)*64 + node]   = o0;
    Xs[(chunk*2+1)*64 + node] = o1;
  }
  // ---- h rows -> Xs rows 16..31
  {
    int node = tid & 63, cg = tid >> 6;
    for (int j=0; j<2; ++j){
      int kb = 16 + cg + 8*j;
      Xs[kb*64 + node] = hb8[(size_t)(node + n0)*16 + (kb-16)];
    }
  }
  __syncthreads();
  // ---- fused zero of this block's agg rows for next round
  {
    f32x4* ap4 = (f32x4*)(agg + (size_t)n0*128);
    f32x4 z = {0.f,0.f,0.f,0.f};
    for (int i = tid; i < 64*128/4; i += 512) ap4[i] = z;
  }
  int w = tid>>6, lane = tid&63, quad = lane>>4, l15 = lane&15;
  f32x4 acc1[4][2];
  for (int a=0;a<4;a++)
    for (int b=0;b<2;b++){ f32x4 z = {0.f,0.f,0.f,0.f}; acc1[a][b]=z; }
  for (int ks=0; ks<8; ++ks){
    u16x8 bv[2], av[4];
    for (int nt=0; nt<2; ++nt)
      bv[nt] = w1tu8[(size_t)(w*32 + nt*16 + l15)*32 + ks*4 + quad];
    for (int mt=0; mt<4; ++mt)
      av[mt] = Xs[(ks*4 + quad)*64 + mt*16 + l15];
    for (int mt=0; mt<4; ++mt)
      for (int nt=0; nt<2; ++nt)
        acc1[mt][nt] = mfma16(av[mt], bv[nt], acc1[mt][nt]);
  }
  __syncthreads();
  for (int mt=0; mt<4; ++mt)
    for (int nt=0; nt<2; ++nt){
      int n = w*32 + nt*16 + l15;
      float bias = b1u[n];
      for (int r=0;r<4;r++){
        int mm = mt*16 + quad*4 + r;
        float v = fmaxf(acc1[mt][nt][r] + bias, 0.f);
        HsB[((n>>3)*64 + mm)*8 + (n&7)] = f2bf(v);
      }
    }
  __syncthreads();
  f32x4 acc2[4];
  for (int a=0;a<4;a++){ f32x4 z = {0.f,0.f,0.f,0.f}; acc2[a]=z; }
  int n2 = w*16 + l15;
  for (int ks=0; ks<8; ++ks){
    u16x8 bv2 = w2tu8[(size_t)n2*32 + ks*4 + quad];
    u16x8 av[4];
    for (int mt=0; mt<4; ++mt)
      av[mt] = Hs[(ks*4 + quad)*64 + mt*16 + l15];
    for (int mt=0; mt<4; ++mt)
      acc2[mt] = mfma16(av[mt], bv2, acc2[mt]);
  }
  float bias = b2u[n2];
  for (int mt=0; mt<4; ++mt)
    for (int r=0;r<4;r++){
      int mm = mt*16 + quad*4 + r;
      size_t idx = (size_t)(n0+mm)*128 + n2;
      float base = bf2f(hb[idx]);
      if (has_hl) base += bf2f(hl[idx]);
      float nv = base + acc2[mt][r] + bias;
      unsigned short hi = f2bf(nv);
      hb[idx] = hi;
      if (has_hl) hl[idx] = f2bf(nv - bf2f(hi));
    }
}

// ============================================================ t-MLP — unchanged
__global__ void __launch_bounds__(256) k_tmlp(
  const unsigned short* hb, const unsigned short* hl, int has_hl,
  const float* fc1f, const float* fc2f,
  const float* fc1b, const float* fc2b, unsigned short* Th, unsigned short* Tl)
{
  __shared__ float Xs[16][128];
  __shared__ float Hsm[16][128];
  int tid = threadIdx.x, wv = tid>>6, lane = tid&63;
  int nodeBase = blockIdx.x*16 + wv*4;
  for (int i=0;i<4;i++){
    size_t base = (size_t)(nodeBase+i)*128 + lane*2;
    float x0 = bf2f(hb[base]), x1 = bf2f(hb[base+1]);
    if (has_hl){ x0 += bf2f(hl[base]); x1 += bf2f(hl[base+1]); }
    Xs[wv*4+i][lane*2] = x0; Xs[wv*4+i][lane*2+1] = x1;
  }
  __syncthreads();
  float a0[4], a1[4];
  for (int i=0;i<4;i++){ a0[i] = fc1b[lane*2]; a1[i] = fc1b[lane*2+1]; }
  for (int k=0;k<128;k++){
    f32x2 w = *(const f32x2*)&fc1f[k*128 + lane*2];
    for (int i=0;i<4;i++){ float x = Xs[wv*4+i][k]; a0[i] += x*w[0]; a1[i] += x*w[1]; }
  }
  for (int i=0;i<4;i++){
    Hsm[wv*4+i][lane*2]   = fmaxf(a0[i], 0.f);
    Hsm[wv*4+i][lane*2+1] = fmaxf(a1[i], 0.f);
  }
  __syncthreads();
  for (int i=0;i<4;i++){ a0[i] = fc2b[lane*2]; a1[i] = fc2b[lane*2+1]; }
  for (int k=0;k<128;k++){
    f32x2 w = *(const f32x2*)&fc2f[k*128 + lane*2];
    for (int i=0;i<4;i++){ float x = Hsm[wv*4+i][k]; a0[i] += x*w[0]; a1[i] += x*w[1]; }
  }
  for (int i=0;i<4;i++){
    size_t idx = (size_t)(nodeBase+i)*128 + lane*2;
    float t0 = a0[i], t1 = a1[i];
    unsigned short h0 = f2bf(t0), h1 = f2bf(t1);
    Th[idx] = h0; Th[idx+1] = h1;
    Tl[idx]   = f2bf(t0 - bf2f(h0));
    Tl[idx+1] = f2bf(t1 - bf2f(h1));
  }
}

// ============================================================ per-pair — unchanged
__global__ void __launch_bounds__(256) k_pair(
  const unsigned short* Th, const unsigned short* Tl,
  const unsigned short* hb, const unsigned short* hl, int has_hl,
  void* outv, const int* flag)
{
  __shared__ float la[8448];
  __shared__ float red[4];
  const u16x8* th8 = (const u16x8*)Th;
  const u16x8* tl8 = (const u16x8*)Tl;
  int b = blockIdx.x;
  int even = ((b & 1) == 0);
  int qs = even ? 128 : 64;
  int cs = 192 - qs;
  int nr = even ? 128 : 65;
  int nc = even ? 65 : 128;
  int st = nc + 1;
  int q0 = 192*b, c0 = q0 + qs;
  int tid = threadIdx.x, wv = tid>>6, lane = tid&63, quad = lane>>4, l15 = lane&15;
  u16x8 zero8 = {0,0,0,0,0,0,0,0};

  f32x4 acc[2][8];
  for (int a=0;a<2;a++)
    for (int c=0;c<8;c++){ f32x4 z = {0.f,0.f,0.f,0.f}; acc[a][c]=z; }
  for (int pass=0; pass<3; ++pass){
    const u16x8* A  = (pass==2) ? tl8 : th8;
    const u16x8* Bm = (pass==1) ? tl8 : th8;
    for (int ks=0; ks<4; ++ks){
      u16x8 av[2], bv[8];
      for (int mt=0; mt<2; ++mt){
        int q = wv*32 + mt*16 + l15;
        av[mt] = (q < qs) ? A[(size_t)(q0+q)*16 + ks*4 + quad] : zero8;
      }
      for (int nt=0; nt<8; ++nt){
        int c = nt*16 + l15;
        bv[nt] = (c < cs) ? Bm[(size_t)(c0+c)*16 + ks*4 + quad] : zero8;
      }
      for (int mt=0; mt<2; ++mt)
        for (int nt=0; nt<8; ++nt)
          acc[mt][nt] = mfma16(av[mt], bv[nt], acc[mt][nt]);
    }
  }
  for (int mt=0; mt<2; ++mt)
    for (int nt=0; nt<8; ++nt)
      for (int r=0;r<4;r++){
        int q = wv*32 + mt*16 + quad*4 + r;
        int c = nt*16 + l15;
        if (q < nr && c < nc) la[q*st + c] = acc[mt][nt][r] * 10.0f;
      }
  __syncthreads();

  for (int it=0; it<20; ++it){
    if (tid < nr){
      float* row = &la[tid*st];
      float mx = -1e30f;
      for (int c=0;c<nc;c++) mx = fmaxf(mx, row[c]);
      float s = 0.f, last = 0.f;
      for (int c=0;c<nc;c++){ float e = __expf(row[c]-mx); s += e; last = e; }
      if (even) s += 63.f * last;
      float l = mx + __logf(s);
      for (int c=0;c<nc;c++) row[c] -= l;
    }
    __syncthreads();
    if (tid < nc){
      int c = tid;
      float mx = -1e30f;
      for (int r=0;r<nr;r++) mx = fmaxf(mx, la[r*st + c]);
      float s = 0.f, last = 0.f;
      for (int r=0;r<nr;r++){ float e = __expf(la[r*st + c]-mx); s += e; last = e; }
      if (!even) s += 63.f * last;
      float l = mx + __logf(s);
      for (int r=0;r<nr;r++) la[r*st + c] -= l;
    }
    __syncthreads();
  }
  for (int i = tid; i < 8448; i += 256) la[i] = __expf(la[i]);
  __syncthreads();

  int d = tid & 127, qg = tid >> 7;
  int nsweep = (nr + 15) >> 4;
  float partial = 0.f;
  for (int sweep=0; sweep<nsweep; ++sweep){
    int qb = sweep*16 + qg*8;
    float acc2[8];
    for (int j=0;j<8;j++) acc2[j] = 0.f;
    for (int c=0; c<cs; ++c){
      size_t si = (size_t)(c0+c)*128 + d;
      float s = bf2f(hb[si]);
      if (has_hl) s += bf2f(hl[si]);
      for (int j=0;j<8;j++){
        int r = qb + j;
        if (r < nr) acc2[j] += la[r*st + c] * s;
      }
    }
    for (int j=0;j<8;j++){
      int r = qb + j;
      if (r < nr){
        float w = (!even && r == 64) ? 64.f : 1.f;
        float sq = 0.f;
        if (r < qs){
          size_t si = (size_t)(q0+r)*128 + d;
          sq = bf2f(hb[si]);
          if (has_hl) sq += bf2f(hl[si]);
        }
        partial += w * fmaxf(sq - acc2[j], 0.f);
      }
    }
  }
  for (int off=32; off>0; off>>=1) partial += __shfl_down(partial, off, 64);
  if (lane == 0) red[wv] = partial;
  __syncthreads();
  if (tid == 0){
    float tot = red[0] + red[1] + red[2] + red[3];
    if (*flag) ((unsigned short*)outv)[b] = f2bf(-tot);
    else       ((float*)outv)[b] = -tot;
  }
}

// ============================================================ host
extern "C" void kernel_launch(void* const* d_in, const int* in_sizes, int n_in,
                              void* d_out, int out_size, void* d_ws, size_t ws_size,
                              hipStream_t stream)
{
  if (ws_size < WS_MINI){
    k_sent<<<2, 256, 0, stream>>>((float*)d_out);
    return;
  }
  int has_hl = 0, use_s8 = 0, use_g2 = 0;
  size_t off_csr = 0;
  if (ws_size >= WS_G2){ has_hl = 1; use_s8 = 1; use_g2 = 1; off_csr = WS_FULL; }
  else if (ws_size >= WS_FULL_G){ has_hl = 1; use_s8 = 1; off_csr = WS_FULL; }
  else if (ws_size >= WS_FULL){ has_hl = 1; use_s8 = 0; }
  else if (ws_size >= WS_MINI_G){ has_hl = 0; use_s8 = 1; off_csr = WS_MINI; }

  const int* from_idx = (const int*)d_in[22];
  const int* to_idx   = (const int*)d_in[23];

  char* wsb = (char*)d_ws;
  unsigned short* hb  = (unsigned short*)(wsb + OFF_HB);
  unsigned short* hl  = (unsigned short*)(wsb + OFF_HL);
  float* agg          = (float*)(wsb + OFF_AGG);
  unsigned short* Th  = (unsigned short*)(wsb + OFF_TH);
  unsigned short* Tl  = (unsigned short*)(wsb + OFF_TL);
  int* flag           = (int*)(wsb + OFF_W + WO_FLAG);

  const unsigned short* w1tm = (const unsigned short*)(wsb + OFF_W + WO_W1TM);
  const unsigned short* w1tr = (const unsigned short*)(wsb + OFF_W + WO_W1TR);
  const unsigned short* w2tm = (const unsigned short*)(wsb + OFF_W + WO_W2TM);
  const unsigned short* w2tr = (const unsigned short*)(wsb + OFF_W + WO_W2TR);
  const unsigned short* w1tu = (const unsigned short*)(wsb + OFF_W + WO_W1TU);
  const unsigned short* w2tu = (const unsigned short*)(wsb + OFF_W + WO_W2TU);
  const unsigned short* wnt  = (const unsigned short*)(wsb + OFF_W + WO_WNT);
  const unsigned short* wetp = (const unsigned short*)(wsb + OFF_W + WO_WETP);
  const float* fc1f  = (const float*)(wsb + OFF_W + WO_FC1F);
  const float* fc2f  = (const float*)(wsb + OFF_W + WO_FC2F);
  const float* bnf   = (const float*)(wsb + OFF_W + WO_BNF);
  const float* bef   = (const float*)(wsb + OFF_W + WO_BEF);
  const float* b1m   = (const float*)(wsb + OFF_W + WO_B1M);
  const float* b2m   = (const float*)(wsb + OFF_W + WO_B2M);
  const float* b1r   = (const float*)(wsb + OFF_W + WO_B1R);
  const float* b2r   = (const float*)(wsb + OFF_W + WO_B2R);
  const float* b1u   = (const float*)(wsb + OFF_W + WO_B1U);
  const float* b2u   = (const float*)(wsb + OFF_W + WO_B2U);
  const float* f1b   = (const float*)(wsb + OFF_W + WO_FC1B);
  const float* f2b   = (const float*)(wsb + OFF_W + WO_FC2B);

  int* offs0 = (int*)(wsb + off_csr);
  int* offs1 = offs0 + (NN + 1);
  int* cur0  = offs1 + (NN + 1);
  int* cur1  = cur0 + NN;
  int* ent0  = cur1 + NN;
  int* ent1  = ent0 + NE;
  int* csum  = ent1 + NE;
  int* inv0  = use_g2 ? (int*)(wsb + OFF_INV0) : (int*)nullptr;
  unsigned short* m1 = (unsigned short*)(wsb + OFF_M1);

  k_dtype<<<1, 64, 0, stream>>>((const unsigned short*)d_in[0], flag);

  k_canary<<<2, 256, 0, stream>>>(d_out, flag);

  k_prep<<<1439, 256, 0, stream>>>(
    d_in[2],  d_in[3],  d_in[4],  d_in[5],
    d_in[6],  d_in[7],  d_in[8],  d_in[9],
    d_in[10], d_in[11], d_in[12], d_in[13],
    d_in[14], d_in[15], d_in[16], d_in[17],
    d_in[18], d_in[19], d_in[20], d_in[21],
    wsb);

  if (use_s8){
    k_csr_zero <<<NN/256, 256, 0, stream>>>(cur0, cur1);
    k_csr_count<<<NE/256, 256, 0, stream>>>(from_idx, to_idx, cur0, cur1);
    k_scan1    <<<2*SCAN_CHUNKS, 256, 0, stream>>>(cur0, cur1, csum);
    k_scan2    <<<1, 128, 0, stream>>>(csum, offs0, offs1);
    k_scan3    <<<2*SCAN_CHUNKS, 256, 0, stream>>>(cur0, cur1, csum, offs0, offs1);
    k_csr_fill <<<NE/256, 256, 0, stream>>>(from_idx, to_idx, cur0, cur1, ent0, ent1, inv0);
  }

  k_enc_node<<<NN/64, 256, 0, stream>>>(d_in[0], wnt, bnf, hb, hl, has_hl, flag);

  k_zero<<<3072, 256, 0, stream>>>(agg);   // round-0 only; later rounds fused into upd
  for (int r=0; r<5; ++r){
    if (use_g2){
      k_msg10<<<NE/64, 512, 0, stream>>>(hb, d_in[1],
          from_idx, to_idx, ent0, w1tm, w1tr, w2tm, w2tr, wetp, bef,
          b1m, b2m, b1r, b2r, agg, m1, flag);
      k_upd2<<<NN/64, 512, 0, stream>>>(agg, m1, ent1, inv0, offs1,
          hb, w1tu, w2tu, b1u, b2u, hb, hl, has_hl);
    } else if (use_s8){
      k_msg8<<<NE/64, 512, 0, stream>>>(hb, d_in[1],
          from_idx, to_idx, ent0, w1tm, w1tr, w2tm, w2tr, wetp, bef,
          b1m, b2m, b1r, b2r, agg, flag);
      k_upd<<<NN/64, 512, 0, stream>>>(agg, hb, w1tu, w2tu, b1u, b2u, hb, hl, has_hl);
    } else {
      k_msg<<<NE/32, 256, 0, stream>>>(hb, d_in[1],
          from_idx, to_idx, w1tm, w1tr, w2tm, w2tr, wetp, bef,
          b1m, b2m, b1r, b2r, agg, flag);
      k_upd<<<NN/64, 512, 0, stream>>>(agg, hb, w1tu, w2tu, b1u, b2u, hb, hl, has_hl);
    }
  }

  k_tmlp<<<NN/16, 256, 0, stream>>>(hb, hl, has_hl, fc1f, fc2f, f1b, f2b, Th, Tl);
  k_pair<<<NB, 256, 0, stream>>>(Th, Tl, hb, hl, has_hl, d_out, flag);
}